// Round 1
// baseline (1399.414 us; speedup 1.0000x reference)
//
#include <hip/hip_runtime.h>

// Problem constants
#define BN_B 64
#define NC 5
#define NH 50
#define NL 32
#define DD 300
#define QQ 200
#define NVOC 50000
#define NGAT 55          // 5 candidate + 50 clicked news GATs
#define NROW 2048        // rows per news GAT (B*L)
#define NUSR 3200        // rows user GAT (B*H)
#define NUSR_PAD 3328    // 13*256
#define CW 304           // prefix array row width (300 data + col300 = denominator)
#define NT_NEWS 128      // 2048/16
#define NT_USER 208      // 3328/16

// ---------------------------------------------------------------------------
// GEMM: C[M,300] = A[M,300] @ B[300,300], fp32 vector, 64x64 tile, BK=20
// ---------------------------------------------------------------------------
__global__ __launch_bounds__(256) void k_gemm300(const float* __restrict__ A,
                                                 const float* __restrict__ B,
                                                 float* __restrict__ C, int M) {
  __shared__ __align__(16) float As[20][68];  // transposed A tile, stride 68 (16B aligned)
  __shared__ __align__(16) float Bs[20][64];
  const int tid = threadIdx.x;
  const int m0 = blockIdx.x * 64, n0 = blockIdx.y * 64;
  const int ty = tid >> 4, tx = tid & 15;
  float acc[4][4] = {};
  for (int k0 = 0; k0 < 300; k0 += 20) {
#pragma unroll
    for (int i = 0; i < 5; ++i) {          // stage A: 64x20
      int idx = tid * 5 + i;
      int m = idx / 20, k = idx % 20;
      int gm = m0 + m;
      As[k][m] = (gm < M) ? A[(size_t)gm * DD + k0 + k] : 0.f;
    }
#pragma unroll
    for (int i = 0; i < 5; ++i) {          // stage B: 20x64
      int idx = i * 256 + tid;
      int k = idx >> 6, n = idx & 63;
      int gn = n0 + n;
      Bs[k][n] = (gn < DD) ? B[(size_t)(k0 + k) * DD + gn] : 0.f;
    }
    __syncthreads();
#pragma unroll
    for (int k = 0; k < 20; ++k) {
      const float4 a4 = *(const float4*)&As[k][ty * 4];
      const float4 b4 = *(const float4*)&Bs[k][tx * 4];
      const float av[4] = {a4.x, a4.y, a4.z, a4.w};
      const float bv[4] = {b4.x, b4.y, b4.z, b4.w};
#pragma unroll
      for (int im = 0; im < 4; ++im)
#pragma unroll
        for (int in = 0; in < 4; ++in)
          acc[im][in] = fmaf(av[im], bv[in], acc[im][in]);
    }
    __syncthreads();
  }
#pragma unroll
  for (int im = 0; im < 4; ++im) {
    int gm = m0 + ty * 4 + im;
    if (gm < M) {
#pragma unroll
      for (int in = 0; in < 4; ++in) {
        int gn = n0 + tx * 4 + in;
        if (gn < DD) C[(size_t)gm * DD + gn] = acc[im][in];
      }
    }
  }
}

// ---------------------------------------------------------------------------
// s1/s2 per row: s1[r] = Wh[r,:]·a[0:300], s2[r] = Wh[r,:]·a[300:600]
// ---------------------------------------------------------------------------
__global__ __launch_bounds__(256) void k_sv(const float* __restrict__ Wh,
                                            const float* __restrict__ avec,
                                            float* __restrict__ s1, float* __restrict__ s2, int M) {
  int row = blockIdx.x * 4 + (threadIdx.x >> 6);
  int lane = threadIdx.x & 63;
  if (row >= M) return;
  const float* wr = Wh + (size_t)row * DD;
  float p1 = 0.f, p2 = 0.f;
  for (int d = lane; d < DD; d += 64) {
    float w = wr[d];
    p1 = fmaf(w, avec[d], p1);
    p2 = fmaf(w, avec[DD + d], p2);
  }
  for (int o = 32; o; o >>= 1) { p1 += __shfl_xor(p1, o, 64); p2 += __shfl_xor(p2, o, 64); }
  if (lane == 0) { s1[row] = p1; s2[row] = p2; }
}

// ---------------------------------------------------------------------------
// Bitonic sort of s2 values (payload = token id / row id) + exp tables
// mode 0: news GAT blockIdx.x = item.  mode 1: user (single block, pad to 4096)
// ---------------------------------------------------------------------------
__global__ __launch_bounds__(1024) void k_sort(const int* __restrict__ cand,
                                               const int* __restrict__ clicked,
                                               const float* __restrict__ s2src,
                                               float* __restrict__ s2s, int* __restrict__ perm,
                                               float* __restrict__ E1, float* __restrict__ E02,
                                               int mode, int N, int SZ, int Epad) {
  __shared__ float sval[4096];
  __shared__ int spay[4096];
  const int m = blockIdx.x;
  const int tid = threadIdx.x;
  float* s2s_g = s2s + (size_t)m * N;
  int* perm_g = perm + (size_t)m * Epad;
  float* E1_g = E1 + (size_t)m * Epad;
  float* E02_g = E02 + (size_t)m * Epad;

  for (int i = tid; i < SZ; i += 1024) {
    float v; int p;
    if (mode == 0) {
      int b = i >> 5, l = i & 31;
      int tok = (m < NC) ? cand[b * (NC * NL) + m * NL + l]
                         : clicked[b * (NH * NL) + (m - NC) * NL + l];
      v = s2src[tok]; p = tok;
    } else {
      if (i < N) { v = s2src[i]; p = i; } else { v = __builtin_inff(); p = 0; }
    }
    sval[i] = v; spay[i] = p;
  }
  __syncthreads();
  for (int k = 2; k <= SZ; k <<= 1) {
    for (int j = k >> 1; j > 0; j >>= 1) {
      for (int i = tid; i < SZ; i += 1024) {
        int ixj = i ^ j;
        if (ixj > i) {
          bool asc = ((i & k) == 0);
          float a = sval[i], bb = sval[ixj];
          bool sw = asc ? (a > bb) : (a < bb);
          if (sw) {
            sval[i] = bb; sval[ixj] = a;
            int t = spay[i]; spay[i] = spay[ixj]; spay[ixj] = t;
          }
        }
      }
      __syncthreads();
    }
  }
  for (int i = tid; i < Epad; i += 1024) {
    float v = sval[i];
    if (i < N) s2s_g[i] = v;
    E1_g[i] = (i < N) ? expf(v) : 0.f;
    E02_g[i] = (i < N) ? expf(0.2f * v) : 0.f;
    perm_g[i] = spay[i];
  }
}

// ---------------------------------------------------------------------------
// Chunked weighted prefix accumulation at granularity 16.
// Writes LOCAL (per-256-chunk) prefixes at positions t = kc*16+1 .. kc*16+16.
// col<300: data col; col==300: denominator (w=1).
// ---------------------------------------------------------------------------
__global__ __launch_bounds__(320) void k_scan(const float* __restrict__ base,
                                              const int* __restrict__ perm,
                                              const float* __restrict__ E1,
                                              const float* __restrict__ E02,
                                              float* __restrict__ C1, float* __restrict__ C02,
                                              int Epad, int cstride) {
  const int g = blockIdx.y, kc = blockIdx.x;
  const int col = threadIdx.x;
  const int* perm_g = perm + (size_t)g * Epad;
  const float* E1_g = E1 + (size_t)g * Epad;
  const float* E02_g = E02 + (size_t)g * Epad;
  float* C1_g = C1 + (size_t)g * cstride * CW;
  float* C02_g = C02 + (size_t)g * cstride * CW;
  const bool datacol = (col < DD);
  const float wden = (col == DD) ? 1.f : 0.f;
  float acc1 = 0.f, acc2 = 0.f;
  const int k0 = kc * 256;
#pragma unroll 8
  for (int kk = 0; kk < 256; ++kk) {
    int k = k0 + kk;
    int tok = perm_g[k];
    float e1 = E1_g[k], e02 = E02_g[k];
    float w = datacol ? base[(size_t)tok * DD + col] : wden;
    acc1 = fmaf(e1, w, acc1);
    acc2 = fmaf(e02, w, acc2);
    if ((kk & 15) == 15) {
      int t = (k + 1) >> 4;
      if (col < CW) { C1_g[(size_t)t * CW + col] = acc1; C02_g[(size_t)t * CW + col] = acc2; }
    }
  }
}

// Fix-up: turn per-chunk local prefixes into global prefixes; row 0 := 0.
__global__ __launch_bounds__(320) void k_fix(float* __restrict__ C1, float* __restrict__ C02,
                                             int nkc, int cstride) {
  const int g = blockIdx.x, col = threadIdx.x;
  if (col >= CW) return;
  float* C1_g = C1 + (size_t)g * cstride * CW;
  float* C02_g = C02 + (size_t)g * cstride * CW;
  C1_g[col] = 0.f; C02_g[col] = 0.f;
  float off1 = 0.f, off2 = 0.f;
  for (int kc = 0; kc < nkc; ++kc) {
    float l1 = 0.f, l2 = 0.f;
    for (int tl = 1; tl <= 16; ++tl) {
      size_t idx = (size_t)(kc * 16 + tl) * CW + col;
      float v1 = C1_g[idx], v2 = C02_g[idx];
      C1_g[idx] = v1 + off1; C02_g[idx] = v2 + off2;
      if (tl == 16) { l1 = v1; l2 = v2; }
    }
    off1 += l1; off2 += l2;
  }
}

// ---------------------------------------------------------------------------
// Per-(item,b) fused: GAT row reconstruction (prefix lookup + <=15 residual
// terms) -> elu -> additive attention -> encoded vector.
// ---------------------------------------------------------------------------
__global__ __launch_bounds__(256) void k_row_news(
    const int* __restrict__ cand, const int* __restrict__ clicked,
    const float* __restrict__ EW, const float* __restrict__ s1v,
    const float* __restrict__ s2s, const int* __restrict__ perm,
    const float* __restrict__ E1, const float* __restrict__ E02,
    const float* __restrict__ C1, const float* __restrict__ C02,
    const float* __restrict__ lin_w, const float* __restrict__ lin_b,
    const float* __restrict__ query,
    float* __restrict__ cand_enc, float* __restrict__ clicked_enc) {
  __shared__ __align__(16) float g_s[32][308];
  __shared__ float part[32][50];
  __shared__ float wgt[32];
  const int b = blockIdx.x, m = blockIdx.y;
  const int tid = threadIdx.x;
  const float* s2s_m = s2s + (size_t)m * NROW;
  const int* perm_m = perm + (size_t)m * NROW;
  const float* E1_m = E1 + (size_t)m * NROW;
  const float* E02_m = E02 + (size_t)m * NROW;
  const float* C1_m = C1 + (size_t)m * (NT_NEWS + 1) * CW;
  const float* C02_m = C02 + (size_t)m * (NT_NEWS + 1) * CW;
  const int wave = tid >> 6, lane = tid & 63;

  for (int il = 0; il < 8; ++il) {
    const int l = wave * 8 + il;
    int tok = (m < NC) ? cand[b * (NC * NL) + m * NL + l]
                       : clicked[b * (NH * NL) + (m - NC) * NL + l];
    float s1 = s1v[tok];
    float es1 = expf(s1), es02 = expf(0.2f * s1);
    float tau = -s1;
    int lo = 0, hi = NROW;
    while (lo < hi) { int mid = (lo + hi) >> 1; if (s2s_m[mid] <= tau) lo = mid + 1; else hi = mid; }
    const int ki = lo, t = ki >> 4, nr = ki & 15, kr0 = t << 4;
    float rd1 = 0.f, rd2 = 0.f;
    float rv1[5] = {0, 0, 0, 0, 0}, rv2[5] = {0, 0, 0, 0, 0};
    for (int r = 0; r < nr; ++r) {
      int tk = perm_m[kr0 + r];
      float e1 = E1_m[kr0 + r], e02 = E02_m[kr0 + r];
      rd1 += e1; rd2 += e02;
      const float* wr = EW + (size_t)tk * DD;
#pragma unroll
      for (int c = 0; c < 5; ++c) {
        int d = lane + 64 * c;
        if (d < DD) { float w = wr[d]; rv1[c] = fmaf(e1, w, rv1[c]); rv2[c] = fmaf(e02, w, rv2[c]); }
      }
    }
    float T1den = C1_m[(size_t)NT_NEWS * CW + DD];
    float den = es1 * (T1den - C1_m[(size_t)t * CW + DD] - rd1) +
                es02 * (C02_m[(size_t)t * CW + DD] + rd2);
    float rden = 1.f / den;
#pragma unroll
    for (int c = 0; c < 5; ++c) {
      int d = lane + 64 * c;
      if (d < DD) {
        float num = es1 * (C1_m[(size_t)NT_NEWS * CW + d] - C1_m[(size_t)t * CW + d] - rv1[c]) +
                    es02 * (C02_m[(size_t)t * CW + d] + rv2[c]);
        float gg = num * rden;
        g_s[l][d] = (gg > 0.f) ? gg : expm1f(gg);
      }
    }
  }
  __syncthreads();

  if (tid < 200) {                       // 4 l-groups x 50 q-groups
    const int lth = tid & 3, qth = tid >> 2;
    float acc[8][4] = {};
    for (int dv = 0; dv < 75; ++dv) {
      float4 w4[4];
#pragma unroll
      for (int iq = 0; iq < 4; ++iq)
        w4[iq] = *(const float4*)&lin_w[(size_t)(qth * 4 + iq) * DD + dv * 4];
#pragma unroll
      for (int il = 0; il < 8; ++il) {
        float4 g4 = *(const float4*)&g_s[lth + 4 * il][dv * 4];
#pragma unroll
        for (int iq = 0; iq < 4; ++iq)
          acc[il][iq] += g4.x * w4[iq].x + g4.y * w4[iq].y + g4.z * w4[iq].z + g4.w * w4[iq].w;
      }
    }
#pragma unroll
    for (int il = 0; il < 8; ++il) {
      float contrib = 0.f;
#pragma unroll
      for (int iq = 0; iq < 4; ++iq) {
        int q = qth * 4 + iq;
        contrib += tanhf(acc[il][iq] + lin_b[q]) * query[q];
      }
      part[lth + 4 * il][qth] = contrib;
    }
  }
  __syncthreads();
  if (tid < 32) {
    float lg = 0.f;
    for (int q = 0; q < 50; ++q) lg += part[tid][q];
    float mx = lg;
    for (int o = 16; o; o >>= 1) mx = fmaxf(mx, __shfl_xor(mx, o, 32));
    float e = expf(lg - mx);
    float sm = e;
    for (int o = 16; o; o >>= 1) sm += __shfl_xor(sm, o, 32);
    wgt[tid] = e / sm;
  }
  __syncthreads();
  float* outp = (m < NC) ? (cand_enc + ((size_t)b * NC + m) * DD)
                         : (clicked_enc + ((size_t)b * NH + (m - NC)) * DD);
  for (int d = tid; d < DD; d += 256) {
    float s = 0.f;
#pragma unroll
    for (int l = 0; l < 32; ++l) s += wgt[l] * g_s[l][d];
    outp[d] = s;
  }
}

// Same idea for the user GAT (50 rows per b, N=3200).
__global__ __launch_bounds__(256) void k_row_user(
    const float* __restrict__ WhU, const float* __restrict__ s1u,
    const float* __restrict__ s2sU, const int* __restrict__ permU,
    const float* __restrict__ E1U, const float* __restrict__ E02U,
    const float* __restrict__ C1U, const float* __restrict__ C02U,
    const float* __restrict__ lin_w, const float* __restrict__ lin_b,
    const float* __restrict__ query, float* __restrict__ user_enc) {
  __shared__ __align__(16) float g_s[50][308];
  __shared__ float logits[50];
  __shared__ float wgt[50];
  const int b = blockIdx.x, tid = threadIdx.x;
  const int wave = tid >> 6, lane = tid & 63;
  if (tid < 50) logits[tid] = 0.f;

  for (int ih = 0;; ++ih) {
    const int h = wave + 4 * ih;
    if (h >= NH) break;
    const int i = b * NH + h;
    float s1 = s1u[i];
    float es1 = expf(s1), es02 = expf(0.2f * s1);
    float tau = -s1;
    int lo = 0, hi = NUSR;
    while (lo < hi) { int mid = (lo + hi) >> 1; if (s2sU[mid] <= tau) lo = mid + 1; else hi = mid; }
    const int ki = lo, t = ki >> 4, nr = ki & 15, kr0 = t << 4;
    float rd1 = 0.f, rd2 = 0.f;
    float rv1[5] = {0, 0, 0, 0, 0}, rv2[5] = {0, 0, 0, 0, 0};
    for (int r = 0; r < nr; ++r) {
      int rk = permU[kr0 + r];
      float e1 = E1U[kr0 + r], e02 = E02U[kr0 + r];
      rd1 += e1; rd2 += e02;
      const float* wr = WhU + (size_t)rk * DD;
#pragma unroll
      for (int c = 0; c < 5; ++c) {
        int d = lane + 64 * c;
        if (d < DD) { float w = wr[d]; rv1[c] = fmaf(e1, w, rv1[c]); rv2[c] = fmaf(e02, w, rv2[c]); }
      }
    }
    float T1den = C1U[(size_t)NT_USER * CW + DD];
    float den = es1 * (T1den - C1U[(size_t)t * CW + DD] - rd1) +
                es02 * (C02U[(size_t)t * CW + DD] + rd2);
    float rden = 1.f / den;
#pragma unroll
    for (int c = 0; c < 5; ++c) {
      int d = lane + 64 * c;
      if (d < DD) {
        float num = es1 * (C1U[(size_t)NT_USER * CW + d] - C1U[(size_t)t * CW + d] - rv1[c]) +
                    es02 * (C02U[(size_t)t * CW + d] + rv2[c]);
        float gg = num * rden;
        g_s[h][d] = (gg > 0.f) ? gg : expm1f(gg);
      }
    }
  }
  __syncthreads();

  if (tid < 250) {                       // 5 l-groups x 50 q-groups
    const int lth = tid / 50, qth = tid % 50;
    float acc[10][4] = {};
    for (int dv = 0; dv < 75; ++dv) {
      float4 w4[4];
#pragma unroll
      for (int iq = 0; iq < 4; ++iq)
        w4[iq] = *(const float4*)&lin_w[(size_t)(qth * 4 + iq) * DD + dv * 4];
#pragma unroll
      for (int il = 0; il < 10; ++il) {
        float4 g4 = *(const float4*)&g_s[lth + 5 * il][dv * 4];
#pragma unroll
        for (int iq = 0; iq < 4; ++iq)
          acc[il][iq] += g4.x * w4[iq].x + g4.y * w4[iq].y + g4.z * w4[iq].z + g4.w * w4[iq].w;
      }
    }
#pragma unroll
    for (int il = 0; il < 10; ++il) {
      float contrib = 0.f;
#pragma unroll
      for (int iq = 0; iq < 4; ++iq) {
        int q = qth * 4 + iq;
        contrib += tanhf(acc[il][iq] + lin_b[q]) * query[q];
      }
      atomicAdd(&logits[lth + 5 * il], contrib);
    }
  }
  __syncthreads();
  if (tid < 64) {
    float lg = (tid < NH) ? logits[tid] : -__builtin_inff();
    float mx = lg;
    for (int o = 32; o; o >>= 1) mx = fmaxf(mx, __shfl_xor(mx, o, 64));
    float e = (tid < NH) ? expf(lg - mx) : 0.f;
    float sm = e;
    for (int o = 32; o; o >>= 1) sm += __shfl_xor(sm, o, 64);
    if (tid < NH) wgt[tid] = e / sm;
  }
  __syncthreads();
  for (int d = tid; d < DD; d += 256) {
    float s = 0.f;
#pragma unroll 10
    for (int h = 0; h < NH; ++h) s += wgt[h] * g_s[h][d];
    user_enc[(size_t)b * DD + d] = s;
  }
}

// Final: out[b,c] = cand_enc[b,c,:]·user_enc[b,:]
__global__ __launch_bounds__(64) void k_dot(const float* __restrict__ cand_enc,
                                            const float* __restrict__ user_enc,
                                            float* __restrict__ out) {
  const int bc = blockIdx.x, b = bc / NC, lane = threadIdx.x;
  const float* cp = cand_enc + (size_t)bc * DD;
  const float* up = user_enc + (size_t)b * DD;
  float s = 0.f;
  for (int d = lane; d < DD; d += 64) s = fmaf(cp[d], up[d], s);
  for (int o = 32; o; o >>= 1) s += __shfl_xor(s, o, 64);
  if (lane == 0) out[bc] = s;
}

// ---------------------------------------------------------------------------
extern "C" void kernel_launch(void* const* d_in, const int* in_sizes, int n_in,
                              void* d_out, int out_size, void* d_ws, size_t ws_size,
                              hipStream_t stream) {
  const int* cand = (const int*)d_in[0];
  const int* clicked = (const int*)d_in[1];
  const float* emb = (const float*)d_in[2];
  const float* news_W = (const float*)d_in[3];
  const float* news_a = (const float*)d_in[4];
  const float* news_lw = (const float*)d_in[5];
  const float* news_lb = (const float*)d_in[6];
  const float* news_q = (const float*)d_in[7];
  const float* user_W = (const float*)d_in[8];
  const float* user_a = (const float*)d_in[9];
  const float* user_lw = (const float*)d_in[10];
  const float* user_lb = (const float*)d_in[11];
  const float* user_q = (const float*)d_in[12];
  float* out = (float*)d_out;

  float* W = (float*)d_ws;
  size_t o = 0;
  auto nxt = [&](size_t n) { size_t c = o; o += (n + 63) & ~(size_t)63; return c; };
  float* EW = W + nxt((size_t)NVOC * DD);
  float* s1v = W + nxt(NVOC);
  float* s2v = W + nxt(NVOC);
  float* s2s = W + nxt((size_t)NGAT * NROW);
  int* perm = (int*)(W + nxt((size_t)NGAT * NROW));
  float* E1 = W + nxt((size_t)NGAT * NROW);
  float* E02 = W + nxt((size_t)NGAT * NROW);
  float* C1 = W + nxt((size_t)NGAT * (NT_NEWS + 1) * CW);
  float* C02 = W + nxt((size_t)NGAT * (NT_NEWS + 1) * CW);
  float* cand_enc = W + nxt((size_t)BN_B * NC * DD);
  float* clicked_enc = W + nxt((size_t)BN_B * NH * DD);
  float* WhU = W + nxt((size_t)NUSR * DD);
  float* s1u = W + nxt(NUSR);
  float* s2u = W + nxt(NUSR);
  float* s2sU = W + nxt(NUSR_PAD);
  int* permU = (int*)(W + nxt(NUSR_PAD));
  float* E1U = W + nxt(NUSR_PAD);
  float* E02U = W + nxt(NUSR_PAD);
  float* C1U = W + nxt((size_t)(NT_USER + 1) * CW);
  float* C02U = W + nxt((size_t)(NT_USER + 1) * CW);
  float* user_enc = W + nxt((size_t)BN_B * DD);

  // 1. EW = emb @ news_W  (all vocab rows; cheaper than per-GAT Wh)
  k_gemm300<<<dim3((NVOC + 63) / 64, 5), 256, 0, stream>>>(emb, news_W, EW, NVOC);
  // 2. per-vocab attention scalars
  k_sv<<<(NVOC + 3) / 4, 256, 0, stream>>>(EW, news_a, s1v, s2v, NVOC);
  // 3. sort s2 per news GAT + exp tables
  k_sort<<<NGAT, 1024, 0, stream>>>(cand, clicked, s2v, s2s, perm, E1, E02, 0, NROW, NROW, NROW);
  // 4-5. coarse (granularity-16) weighted prefix sums
  k_scan<<<dim3(8, NGAT), 320, 0, stream>>>(EW, perm, E1, E02, C1, C02, NROW, NT_NEWS + 1);
  k_fix<<<NGAT, 320, 0, stream>>>(C1, C02, 8, NT_NEWS + 1);
  // 6. fused GAT rows + additive attention -> cand/clicked encodings
  k_row_news<<<dim3(BN_B, NGAT), 256, 0, stream>>>(cand, clicked, EW, s1v, s2s, perm, E1, E02,
                                                   C1, C02, news_lw, news_lb, news_q,
                                                   cand_enc, clicked_enc);
  // 7-11. user GAT over clicked encodings
  k_gemm300<<<dim3(NUSR / 64, 5), 256, 0, stream>>>(clicked_enc, user_W, WhU, NUSR);
  k_sv<<<NUSR / 4, 256, 0, stream>>>(WhU, user_a, s1u, s2u, NUSR);
  k_sort<<<1, 1024, 0, stream>>>(nullptr, nullptr, s2u, s2sU, permU, E1U, E02U, 1, NUSR, 4096, NUSR_PAD);
  k_scan<<<dim3(13, 1), 320, 0, stream>>>(WhU, permU, E1U, E02U, C1U, C02U, NUSR_PAD, NT_USER + 1);
  k_fix<<<1, 320, 0, stream>>>(C1U, C02U, 13, NT_USER + 1);
  // 12. user rows + additive attention
  k_row_user<<<BN_B, 256, 0, stream>>>(WhU, s1u, s2sU, permU, E1U, E02U, C1U, C02U,
                                       user_lw, user_lb, user_q, user_enc);
  // 13. click score
  k_dot<<<BN_B * NC, 64, 0, stream>>>(cand_enc, user_enc, out);
}

// Round 2
// 1150.008 us; speedup vs baseline: 1.2169x; 1.2169x over previous
//
#include <hip/hip_runtime.h>
#include <hip/hip_bf16.h>

// Problem constants
#define BN_B 64
#define NC 5
#define NH 50
#define NL 32
#define DD 300
#define QQ 200
#define NVOC 50000
#define NGAT 55          // 5 candidate + 50 clicked news GATs
#define NROW 2048        // rows per news GAT (B*L)
#define NUSR 3200        // rows user GAT (B*H)
#define NUSR_PAD 3328    // 13*256
#define CW 304           // prefix array row width (300 data + col300 = denominator)
#define NT_NEWS 128      // 2048/16
#define NT_USER 208      // 3328/16

// ---------------------------------------------------------------------------
// GEMM: C[M,300] = A[M,300] @ B[300,300], fp32 vector, 64x64 tile, BK=20
// ---------------------------------------------------------------------------
__global__ __launch_bounds__(256) void k_gemm300(const float* __restrict__ A,
                                                 const float* __restrict__ B,
                                                 float* __restrict__ C, int M) {
  __shared__ __align__(16) float As[20][68];
  __shared__ __align__(16) float Bs[20][64];
  const int tid = threadIdx.x;
  const int m0 = blockIdx.x * 64, n0 = blockIdx.y * 64;
  const int ty = tid >> 4, tx = tid & 15;
  float acc[4][4] = {};
  for (int k0 = 0; k0 < 300; k0 += 20) {
#pragma unroll
    for (int i = 0; i < 5; ++i) {          // stage A: 64x20
      int idx = tid * 5 + i;
      int m = idx / 20, k = idx % 20;
      int gm = m0 + m;
      As[k][m] = (gm < M) ? A[(size_t)gm * DD + k0 + k] : 0.f;
    }
#pragma unroll
    for (int i = 0; i < 5; ++i) {          // stage B: 20x64
      int idx = i * 256 + tid;
      int k = idx >> 6, n = idx & 63;
      int gn = n0 + n;
      Bs[k][n] = (gn < DD) ? B[(size_t)(k0 + k) * DD + gn] : 0.f;
    }
    __syncthreads();
#pragma unroll
    for (int k = 0; k < 20; ++k) {
      const float4 a4 = *(const float4*)&As[k][ty * 4];
      const float4 b4 = *(const float4*)&Bs[k][tx * 4];
      const float av[4] = {a4.x, a4.y, a4.z, a4.w};
      const float bv[4] = {b4.x, b4.y, b4.z, b4.w};
#pragma unroll
      for (int im = 0; im < 4; ++im)
#pragma unroll
        for (int in = 0; in < 4; ++in)
          acc[im][in] = fmaf(av[im], bv[in], acc[im][in]);
    }
    __syncthreads();
  }
#pragma unroll
  for (int im = 0; im < 4; ++im) {
    int gm = m0 + ty * 4 + im;
    if (gm < M) {
#pragma unroll
      for (int in = 0; in < 4; ++in) {
        int gn = n0 + tx * 4 + in;
        if (gn < DD) C[(size_t)gm * DD + gn] = acc[im][in];
      }
    }
  }
}

// ---------------------------------------------------------------------------
// s1/s2 per row
// ---------------------------------------------------------------------------
__global__ __launch_bounds__(256) void k_sv(const float* __restrict__ Wh,
                                            const float* __restrict__ avec,
                                            float* __restrict__ s1, float* __restrict__ s2, int M) {
  int row = blockIdx.x * 4 + (threadIdx.x >> 6);
  int lane = threadIdx.x & 63;
  if (row >= M) return;
  const float* wr = Wh + (size_t)row * DD;
  float p1 = 0.f, p2 = 0.f;
  for (int d = lane; d < DD; d += 64) {
    float w = wr[d];
    p1 = fmaf(w, avec[d], p1);
    p2 = fmaf(w, avec[DD + d], p2);
  }
  for (int o = 32; o; o >>= 1) { p1 += __shfl_xor(p1, o, 64); p2 += __shfl_xor(p2, o, 64); }
  if (lane == 0) { s1[row] = p1; s2[row] = p2; }
}

// ---------------------------------------------------------------------------
// Bitonic sort of s2 values + exp tables
// ---------------------------------------------------------------------------
__global__ __launch_bounds__(1024) void k_sort(const int* __restrict__ cand,
                                               const int* __restrict__ clicked,
                                               const float* __restrict__ s2src,
                                               float* __restrict__ s2s, int* __restrict__ perm,
                                               float* __restrict__ E1, float* __restrict__ E02,
                                               int mode, int N, int SZ, int Epad) {
  __shared__ float sval[4096];
  __shared__ int spay[4096];
  const int m = blockIdx.x;
  const int tid = threadIdx.x;
  float* s2s_g = s2s + (size_t)m * N;
  int* perm_g = perm + (size_t)m * Epad;
  float* E1_g = E1 + (size_t)m * Epad;
  float* E02_g = E02 + (size_t)m * Epad;

  for (int i = tid; i < SZ; i += 1024) {
    float v; int p;
    if (mode == 0) {
      int b = i >> 5, l = i & 31;
      int tok = (m < NC) ? cand[b * (NC * NL) + m * NL + l]
                         : clicked[b * (NH * NL) + (m - NC) * NL + l];
      v = s2src[tok]; p = tok;
    } else {
      if (i < N) { v = s2src[i]; p = i; } else { v = __builtin_inff(); p = 0; }
    }
    sval[i] = v; spay[i] = p;
  }
  __syncthreads();
  for (int k = 2; k <= SZ; k <<= 1) {
    for (int j = k >> 1; j > 0; j >>= 1) {
      for (int i = tid; i < SZ; i += 1024) {
        int ixj = i ^ j;
        if (ixj > i) {
          bool asc = ((i & k) == 0);
          float a = sval[i], bb = sval[ixj];
          bool sw = asc ? (a > bb) : (a < bb);
          if (sw) {
            sval[i] = bb; sval[ixj] = a;
            int t = spay[i]; spay[i] = spay[ixj]; spay[ixj] = t;
          }
        }
      }
      __syncthreads();
    }
  }
  for (int i = tid; i < Epad; i += 1024) {
    float v = sval[i];
    if (i < N) s2s_g[i] = v;
    E1_g[i] = (i < N) ? expf(v) : 0.f;
    E02_g[i] = (i < N) ? expf(0.2f * v) : 0.f;
    perm_g[i] = spay[i];
  }
}

// ---------------------------------------------------------------------------
// Chunked weighted prefix accumulation at granularity 16 (local prefixes).
// ---------------------------------------------------------------------------
__global__ __launch_bounds__(320) void k_scan(const float* __restrict__ base,
                                              const int* __restrict__ perm,
                                              const float* __restrict__ E1,
                                              const float* __restrict__ E02,
                                              float* __restrict__ C1, float* __restrict__ C02,
                                              int Epad, int cstride) {
  const int g = blockIdx.y, kc = blockIdx.x;
  const int col = threadIdx.x;
  const int* perm_g = perm + (size_t)g * Epad;
  const float* E1_g = E1 + (size_t)g * Epad;
  const float* E02_g = E02 + (size_t)g * Epad;
  float* C1_g = C1 + (size_t)g * cstride * CW;
  float* C02_g = C02 + (size_t)g * cstride * CW;
  const bool datacol = (col < DD);
  const float wden = (col == DD) ? 1.f : 0.f;
  float acc1 = 0.f, acc2 = 0.f;
  const int k0 = kc * 256;
#pragma unroll 8
  for (int kk = 0; kk < 256; ++kk) {
    int k = k0 + kk;
    int tok = perm_g[k];
    float e1 = E1_g[k], e02 = E02_g[k];
    float w = datacol ? base[(size_t)tok * DD + col] : wden;
    acc1 = fmaf(e1, w, acc1);
    acc2 = fmaf(e02, w, acc2);
    if ((kk & 15) == 15) {
      int t = (k + 1) >> 4;
      if (col < CW) { C1_g[(size_t)t * CW + col] = acc1; C02_g[(size_t)t * CW + col] = acc2; }
    }
  }
}

// Fix-up: local -> global prefixes; row 0 := 0.
__global__ __launch_bounds__(320) void k_fix(float* __restrict__ C1, float* __restrict__ C02,
                                             int nkc, int cstride) {
  const int g = blockIdx.x, col = threadIdx.x;
  if (col >= CW) return;
  float* C1_g = C1 + (size_t)g * cstride * CW;
  float* C02_g = C02 + (size_t)g * cstride * CW;
  C1_g[col] = 0.f; C02_g[col] = 0.f;
  float off1 = 0.f, off2 = 0.f;
  for (int kc = 0; kc < nkc; ++kc) {
    float l1 = 0.f, l2 = 0.f;
    for (int tl = 1; tl <= 16; ++tl) {
      size_t idx = (size_t)(kc * 16 + tl) * CW + col;
      float v1 = C1_g[idx], v2 = C02_g[idx];
      C1_g[idx] = v1 + off1; C02_g[idx] = v2 + off2;
      if (tl == 16) { l1 = v1; l2 = v2; }
    }
    off1 += l1; off2 += l2;
  }
}

// ---------------------------------------------------------------------------
// GAT row construction, high-parallelism: one wave computes 2 rows.
// Sorted s2 staged in LDS so the rank search is LDS-broadcast, not global.
// grid = (ceil(N/8), ngat). Writes post-elu g rows as bf16.
// ---------------------------------------------------------------------------
__global__ __launch_bounds__(256) void k_rows(
    const int* __restrict__ cand, const int* __restrict__ clicked,
    const float* __restrict__ base, const float* __restrict__ s1src,
    const float* __restrict__ s2s, const int* __restrict__ perm,
    const float* __restrict__ E1, const float* __restrict__ E02,
    const float* __restrict__ C1, const float* __restrict__ C02,
    __hip_bfloat16* __restrict__ gout,
    int mode, int N, int NT, int Epad) {
  __shared__ float s2l[NUSR];
  const int m = blockIdx.y, chunk = blockIdx.x;
  const int tid = threadIdx.x;
  const int wave = tid >> 6, lane = tid & 63;
  const float* s2s_m = s2s + (size_t)m * N;
  const int* perm_m = perm + (size_t)m * Epad;
  const float* E1_m = E1 + (size_t)m * Epad;
  const float* E02_m = E02 + (size_t)m * Epad;
  const float* C1_m = C1 + (size_t)m * (NT + 1) * CW;
  const float* C02_m = C02 + (size_t)m * (NT + 1) * CW;
  for (int i = tid; i < N; i += 256) s2l[i] = s2s_m[i];
  __syncthreads();
  const float T1den = C1_m[(size_t)NT * CW + DD];

  for (int sub = 0; sub < 2; ++sub) {
    const int r = chunk * 8 + wave * 2 + sub;
    if (r >= N) continue;
    int tok;
    if (mode == 0) {
      int b = r >> 5, l = r & 31;
      tok = (m < NC) ? cand[b * (NC * NL) + m * NL + l]
                     : clicked[b * (NH * NL) + (m - NC) * NL + l];
    } else {
      tok = r;
    }
    float s1 = s1src[tok];
    float es1 = expf(s1), es02 = expf(0.2f * s1);
    float tau = -s1;
    int lo = 0, hi = N;
    while (lo < hi) { int mid = (lo + hi) >> 1; if (s2l[mid] <= tau) lo = mid + 1; else hi = mid; }
    const int ki = lo, t = ki >> 4, nr = ki & 15, kr0 = t << 4;
    float rd1 = 0.f, rd2 = 0.f;
    float rv1[5] = {0, 0, 0, 0, 0}, rv2[5] = {0, 0, 0, 0, 0};
    for (int rr = 0; rr < nr; ++rr) {
      int tk = perm_m[kr0 + rr];
      float e1 = E1_m[kr0 + rr], e02 = E02_m[kr0 + rr];
      rd1 += e1; rd2 += e02;
      const float* wr = base + (size_t)tk * DD;
#pragma unroll
      for (int c = 0; c < 5; ++c) {
        int d = lane + 64 * c;
        if (d < DD) { float w = wr[d]; rv1[c] = fmaf(e1, w, rv1[c]); rv2[c] = fmaf(e02, w, rv2[c]); }
      }
    }
    float den = es1 * (T1den - C1_m[(size_t)t * CW + DD] - rd1) +
                es02 * (C02_m[(size_t)t * CW + DD] + rd2);
    float rden = 1.f / den;
    __hip_bfloat16* gr = gout + ((size_t)m * N + r) * DD;
#pragma unroll
    for (int c = 0; c < 5; ++c) {
      int d = lane + 64 * c;
      if (d < DD) {
        float num = es1 * (C1_m[(size_t)NT * CW + d] - C1_m[(size_t)t * CW + d] - rv1[c]) +
                    es02 * (C02_m[(size_t)t * CW + d] + rv2[c]);
        float gg = num * rden;
        float ev = (gg > 0.f) ? gg : expm1f(gg);
        gr[d] = __float2bfloat16(ev);
      }
    }
  }
}

// ---------------------------------------------------------------------------
// Additive attention per (b, m): load 32x300 g tile (bf16) -> LDS fp32,
// GEMM vs lin_w, tanh, query dot, softmax over 32, weighted sum.
// ---------------------------------------------------------------------------
__global__ __launch_bounds__(256) void k_attn(
    const __hip_bfloat16* __restrict__ g,
    const float* __restrict__ lin_w, const float* __restrict__ lin_b,
    const float* __restrict__ query,
    float* __restrict__ cand_enc, float* __restrict__ clicked_enc) {
  __shared__ __align__(16) float g_s[32][308];
  __shared__ float part[32][50];
  __shared__ float wgt[32];
  const int b = blockIdx.x, m = blockIdx.y;
  const int tid = threadIdx.x;
  const __hip_bfloat16* gsrc = g + ((size_t)m * NROW + b * NL) * DD;

  for (int idx = tid; idx < 2400; idx += 256) {   // 32 rows x 75 float4-chunks
    int row = idx / 75, c = idx % 75;
    uint2 u = *(const uint2*)(gsrc + (size_t)row * DD + c * 4);
    g_s[row][c * 4 + 0] = __uint_as_float(u.x << 16);
    g_s[row][c * 4 + 1] = __uint_as_float(u.x & 0xffff0000u);
    g_s[row][c * 4 + 2] = __uint_as_float(u.y << 16);
    g_s[row][c * 4 + 3] = __uint_as_float(u.y & 0xffff0000u);
  }
  __syncthreads();

  if (tid < 200) {                       // 4 l-groups x 50 q-groups
    const int lth = tid & 3, qth = tid >> 2;
    float acc[8][4] = {};
    for (int dv = 0; dv < 75; ++dv) {
      float4 w4[4];
#pragma unroll
      for (int iq = 0; iq < 4; ++iq)
        w4[iq] = *(const float4*)&lin_w[(size_t)(qth * 4 + iq) * DD + dv * 4];
#pragma unroll
      for (int il = 0; il < 8; ++il) {
        float4 g4 = *(const float4*)&g_s[lth + 4 * il][dv * 4];
#pragma unroll
        for (int iq = 0; iq < 4; ++iq)
          acc[il][iq] += g4.x * w4[iq].x + g4.y * w4[iq].y + g4.z * w4[iq].z + g4.w * w4[iq].w;
      }
    }
#pragma unroll
    for (int il = 0; il < 8; ++il) {
      float contrib = 0.f;
#pragma unroll
      for (int iq = 0; iq < 4; ++iq) {
        int q = qth * 4 + iq;
        contrib += tanhf(acc[il][iq] + lin_b[q]) * query[q];
      }
      part[lth + 4 * il][qth] = contrib;
    }
  }
  __syncthreads();
  if (tid < 32) {
    float lg = 0.f;
    for (int q = 0; q < 50; ++q) lg += part[tid][q];
    float mx = lg;
    for (int o = 16; o; o >>= 1) mx = fmaxf(mx, __shfl_xor(mx, o, 32));
    float e = expf(lg - mx);
    float sm = e;
    for (int o = 16; o; o >>= 1) sm += __shfl_xor(sm, o, 32);
    wgt[tid] = e / sm;
  }
  __syncthreads();
  float* outp = (m < NC) ? (cand_enc + ((size_t)b * NC + m) * DD)
                         : (clicked_enc + ((size_t)b * NH + (m - NC)) * DD);
  for (int d = tid; d < DD; d += 256) {
    float s = 0.f;
#pragma unroll
    for (int l = 0; l < 32; ++l) s += wgt[l] * g_s[l][d];
    outp[d] = s;
  }
}

// User additive attention per b: 50 rows.
__global__ __launch_bounds__(256) void k_attn_user(
    const __hip_bfloat16* __restrict__ g,
    const float* __restrict__ lin_w, const float* __restrict__ lin_b,
    const float* __restrict__ query, float* __restrict__ user_enc) {
  __shared__ __align__(16) float g_s[50][308];
  __shared__ float logits[50];
  __shared__ float wgt[50];
  const int b = blockIdx.x, tid = threadIdx.x;
  if (tid < 50) logits[tid] = 0.f;
  const __hip_bfloat16* gsrc = g + (size_t)b * NH * DD;
  for (int idx = tid; idx < 3750; idx += 256) {   // 50 rows x 75 chunks
    int row = idx / 75, c = idx % 75;
    uint2 u = *(const uint2*)(gsrc + (size_t)row * DD + c * 4);
    g_s[row][c * 4 + 0] = __uint_as_float(u.x << 16);
    g_s[row][c * 4 + 1] = __uint_as_float(u.x & 0xffff0000u);
    g_s[row][c * 4 + 2] = __uint_as_float(u.y << 16);
    g_s[row][c * 4 + 3] = __uint_as_float(u.y & 0xffff0000u);
  }
  __syncthreads();

  if (tid < 250) {                       // 5 l-groups x 50 q-groups
    const int lth = tid / 50, qth = tid % 50;
    float acc[10][4] = {};
    for (int dv = 0; dv < 75; ++dv) {
      float4 w4[4];
#pragma unroll
      for (int iq = 0; iq < 4; ++iq)
        w4[iq] = *(const float4*)&lin_w[(size_t)(qth * 4 + iq) * DD + dv * 4];
#pragma unroll
      for (int il = 0; il < 10; ++il) {
        float4 g4 = *(const float4*)&g_s[lth + 5 * il][dv * 4];
#pragma unroll
        for (int iq = 0; iq < 4; ++iq)
          acc[il][iq] += g4.x * w4[iq].x + g4.y * w4[iq].y + g4.z * w4[iq].z + g4.w * w4[iq].w;
      }
    }
#pragma unroll
    for (int il = 0; il < 10; ++il) {
      float contrib = 0.f;
#pragma unroll
      for (int iq = 0; iq < 4; ++iq) {
        int q = qth * 4 + iq;
        contrib += tanhf(acc[il][iq] + lin_b[q]) * query[q];
      }
      atomicAdd(&logits[lth + 5 * il], contrib);
    }
  }
  __syncthreads();
  if (tid < 64) {
    float lg = (tid < NH) ? logits[tid] : -__builtin_inff();
    float mx = lg;
    for (int o = 32; o; o >>= 1) mx = fmaxf(mx, __shfl_xor(mx, o, 64));
    float e = (tid < NH) ? expf(lg - mx) : 0.f;
    float sm = e;
    for (int o = 32; o; o >>= 1) sm += __shfl_xor(sm, o, 64);
    if (tid < NH) wgt[tid] = e / sm;
  }
  __syncthreads();
  for (int d = tid; d < DD; d += 256) {
    float s = 0.f;
#pragma unroll 10
    for (int h = 0; h < NH; ++h) s += wgt[h] * g_s[h][d];
    user_enc[(size_t)b * DD + d] = s;
  }
}

// Final: out[b,c] = cand_enc[b,c,:]·user_enc[b,:]
__global__ __launch_bounds__(64) void k_dot(const float* __restrict__ cand_enc,
                                            const float* __restrict__ user_enc,
                                            float* __restrict__ out) {
  const int bc = blockIdx.x, b = bc / NC, lane = threadIdx.x;
  const float* cp = cand_enc + (size_t)bc * DD;
  const float* up = user_enc + (size_t)b * DD;
  float s = 0.f;
  for (int d = lane; d < DD; d += 64) s = fmaf(cp[d], up[d], s);
  for (int o = 32; o; o >>= 1) s += __shfl_xor(s, o, 64);
  if (lane == 0) out[bc] = s;
}

// ---------------------------------------------------------------------------
extern "C" void kernel_launch(void* const* d_in, const int* in_sizes, int n_in,
                              void* d_out, int out_size, void* d_ws, size_t ws_size,
                              hipStream_t stream) {
  const int* cand = (const int*)d_in[0];
  const int* clicked = (const int*)d_in[1];
  const float* emb = (const float*)d_in[2];
  const float* news_W = (const float*)d_in[3];
  const float* news_a = (const float*)d_in[4];
  const float* news_lw = (const float*)d_in[5];
  const float* news_lb = (const float*)d_in[6];
  const float* news_q = (const float*)d_in[7];
  const float* user_W = (const float*)d_in[8];
  const float* user_a = (const float*)d_in[9];
  const float* user_lw = (const float*)d_in[10];
  const float* user_lb = (const float*)d_in[11];
  const float* user_q = (const float*)d_in[12];
  float* out = (float*)d_out;

  float* W = (float*)d_ws;
  size_t o = 0;
  auto nxt = [&](size_t n) { size_t c = o; o += (n + 63) & ~(size_t)63; return c; };
  float* EW = W + nxt((size_t)NVOC * DD);
  float* s1v = W + nxt(NVOC);
  float* s2v = W + nxt(NVOC);
  float* s2s = W + nxt((size_t)NGAT * NROW);
  int* perm = (int*)(W + nxt((size_t)NGAT * NROW));
  float* E1 = W + nxt((size_t)NGAT * NROW);
  float* E02 = W + nxt((size_t)NGAT * NROW);
  float* C1 = W + nxt((size_t)NGAT * (NT_NEWS + 1) * CW);
  float* C02 = W + nxt((size_t)NGAT * (NT_NEWS + 1) * CW);
  float* cand_enc = W + nxt((size_t)BN_B * NC * DD);
  float* clicked_enc = W + nxt((size_t)BN_B * NH * DD);
  float* WhU = W + nxt((size_t)NUSR * DD);
  float* s1u = W + nxt(NUSR);
  float* s2u = W + nxt(NUSR);
  float* s2sU = W + nxt(NUSR_PAD);
  int* permU = (int*)(W + nxt(NUSR_PAD));
  float* E1U = W + nxt(NUSR_PAD);
  float* E02U = W + nxt(NUSR_PAD);
  float* C1U = W + nxt((size_t)(NT_USER + 1) * CW);
  float* C02U = W + nxt((size_t)(NT_USER + 1) * CW);
  float* user_enc = W + nxt((size_t)BN_B * DD);
  __hip_bfloat16* g_news = (__hip_bfloat16*)(W + nxt((size_t)NGAT * NROW * DD / 2));
  __hip_bfloat16* g_user = (__hip_bfloat16*)(W + nxt((size_t)NUSR * DD / 2));

  // 1. EW = emb @ news_W
  k_gemm300<<<dim3((NVOC + 63) / 64, 5), 256, 0, stream>>>(emb, news_W, EW, NVOC);
  // 2. per-vocab attention scalars
  k_sv<<<(NVOC + 3) / 4, 256, 0, stream>>>(EW, news_a, s1v, s2v, NVOC);
  // 3. sort s2 per news GAT + exp tables
  k_sort<<<NGAT, 1024, 0, stream>>>(cand, clicked, s2v, s2s, perm, E1, E02, 0, NROW, NROW, NROW);
  // 4-5. coarse (granularity-16) weighted prefix sums
  k_scan<<<dim3(8, NGAT), 320, 0, stream>>>(EW, perm, E1, E02, C1, C02, NROW, NT_NEWS + 1);
  k_fix<<<NGAT, 320, 0, stream>>>(C1, C02, 8, NT_NEWS + 1);
  // 6. GAT rows (high-parallelism) -> g_news (bf16)
  k_rows<<<dim3(NROW / 8, NGAT), 256, 0, stream>>>(cand, clicked, EW, s1v, s2s, perm, E1, E02,
                                                   C1, C02, g_news, 0, NROW, NT_NEWS, NROW);
  // 7. additive attention -> cand/clicked encodings
  k_attn<<<dim3(BN_B, NGAT), 256, 0, stream>>>(g_news, news_lw, news_lb, news_q,
                                               cand_enc, clicked_enc);
  // 8-12. user GAT over clicked encodings
  k_gemm300<<<dim3(NUSR / 64, 5), 256, 0, stream>>>(clicked_enc, user_W, WhU, NUSR);
  k_sv<<<NUSR / 4, 256, 0, stream>>>(WhU, user_a, s1u, s2u, NUSR);
  k_sort<<<1, 1024, 0, stream>>>(nullptr, nullptr, s2u, s2sU, permU, E1U, E02U, 1, NUSR, 4096, NUSR_PAD);
  k_scan<<<dim3(13, 1), 320, 0, stream>>>(WhU, permU, E1U, E02U, C1U, C02U, NUSR_PAD, NT_USER + 1);
  k_fix<<<1, 320, 0, stream>>>(C1U, C02U, 13, NT_USER + 1);
  k_rows<<<dim3((NUSR + 7) / 8, 1), 256, 0, stream>>>(nullptr, nullptr, WhU, s1u, s2sU, permU,
                                                      E1U, E02U, C1U, C02U, g_user,
                                                      1, NUSR, NT_USER, NUSR_PAD);
  // 13. user additive attention
  k_attn_user<<<BN_B, 256, 0, stream>>>(g_user, user_lw, user_lb, user_q, user_enc);
  // 14. click score
  k_dot<<<BN_B * NC, 64, 0, stream>>>(cand_enc, user_enc, out);
}

// Round 3
// 928.155 us; speedup vs baseline: 1.5077x; 1.2390x over previous
//
#include <hip/hip_runtime.h>
#include <hip/hip_bf16.h>

// Problem constants
#define BN_B 64
#define NC 5
#define NH 50
#define NL 32
#define DD 300
#define QQ 200
#define NVOC 50000
#define NGAT 55          // 5 candidate + 50 clicked news GATs
#define NROW 2048        // rows per news GAT (B*L)
#define NUSR 3200        // rows user GAT (B*H)
#define NUSR_PAD 3328    // 13*256
#define CW 304           // prefix array row width (300 data + col300 = denominator)
#define NT_NEWS 128      // 2048/16
#define NT_USER 208      // 3328/16
#define GSTR 320         // padded g row stride (10 K-tiles of 32 for MFMA)
#define NTILES_N 13      // ceil(200/16)
#define KTILES 10        // 320/32
#define BPELT (NTILES_N * KTILES * 64)  // B-fragment entries (x8 bf16 each)

typedef short bf16x8 __attribute__((ext_vector_type(8)));
typedef float f32x4 __attribute__((ext_vector_type(4)));

// ---------------------------------------------------------------------------
// GEMM: C[M,300] = A[M,300] @ B[300,300], fp32 vector, 64x64 tile, BK=20
// ---------------------------------------------------------------------------
__global__ __launch_bounds__(256) void k_gemm300(const float* __restrict__ A,
                                                 const float* __restrict__ B,
                                                 float* __restrict__ C, int M) {
  __shared__ __align__(16) float As[20][68];
  __shared__ __align__(16) float Bs[20][64];
  const int tid = threadIdx.x;
  const int m0 = blockIdx.x * 64, n0 = blockIdx.y * 64;
  const int ty = tid >> 4, tx = tid & 15;
  float acc[4][4] = {};
  for (int k0 = 0; k0 < 300; k0 += 20) {
#pragma unroll
    for (int i = 0; i < 5; ++i) {          // stage A: 64x20
      int idx = tid * 5 + i;
      int m = idx / 20, k = idx % 20;
      int gm = m0 + m;
      As[k][m] = (gm < M) ? A[(size_t)gm * DD + k0 + k] : 0.f;
    }
#pragma unroll
    for (int i = 0; i < 5; ++i) {          // stage B: 20x64
      int idx = i * 256 + tid;
      int k = idx >> 6, n = idx & 63;
      int gn = n0 + n;
      Bs[k][n] = (gn < DD) ? B[(size_t)(k0 + k) * DD + gn] : 0.f;
    }
    __syncthreads();
#pragma unroll
    for (int k = 0; k < 20; ++k) {
      const float4 a4 = *(const float4*)&As[k][ty * 4];
      const float4 b4 = *(const float4*)&Bs[k][tx * 4];
      const float av[4] = {a4.x, a4.y, a4.z, a4.w};
      const float bv[4] = {b4.x, b4.y, b4.z, b4.w};
#pragma unroll
      for (int im = 0; im < 4; ++im)
#pragma unroll
        for (int in = 0; in < 4; ++in)
          acc[im][in] = fmaf(av[im], bv[in], acc[im][in]);
    }
    __syncthreads();
  }
#pragma unroll
  for (int im = 0; im < 4; ++im) {
    int gm = m0 + ty * 4 + im;
    if (gm < M) {
#pragma unroll
      for (int in = 0; in < 4; ++in) {
        int gn = n0 + tx * 4 + in;
        if (gn < DD) C[(size_t)gm * DD + gn] = acc[im][in];
      }
    }
  }
}

// ---------------------------------------------------------------------------
// s1/s2 per row
// ---------------------------------------------------------------------------
__global__ __launch_bounds__(256) void k_sv(const float* __restrict__ Wh,
                                            const float* __restrict__ avec,
                                            float* __restrict__ s1, float* __restrict__ s2, int M) {
  int row = blockIdx.x * 4 + (threadIdx.x >> 6);
  int lane = threadIdx.x & 63;
  if (row >= M) return;
  const float* wr = Wh + (size_t)row * DD;
  float p1 = 0.f, p2 = 0.f;
  for (int d = lane; d < DD; d += 64) {
    float w = wr[d];
    p1 = fmaf(w, avec[d], p1);
    p2 = fmaf(w, avec[DD + d], p2);
  }
  for (int o = 32; o; o >>= 1) { p1 += __shfl_xor(p1, o, 64); p2 += __shfl_xor(p2, o, 64); }
  if (lane == 0) { s1[row] = p1; s2[row] = p2; }
}

// ---------------------------------------------------------------------------
// Bitonic sort of s2 values + exp tables
// ---------------------------------------------------------------------------
__global__ __launch_bounds__(1024) void k_sort(const int* __restrict__ cand,
                                               const int* __restrict__ clicked,
                                               const float* __restrict__ s2src,
                                               float* __restrict__ s2s, int* __restrict__ perm,
                                               float* __restrict__ E1, float* __restrict__ E02,
                                               int mode, int N, int SZ, int Epad) {
  __shared__ float sval[4096];
  __shared__ int spay[4096];
  const int m = blockIdx.x;
  const int tid = threadIdx.x;
  float* s2s_g = s2s + (size_t)m * N;
  int* perm_g = perm + (size_t)m * Epad;
  float* E1_g = E1 + (size_t)m * Epad;
  float* E02_g = E02 + (size_t)m * Epad;

  for (int i = tid; i < SZ; i += 1024) {
    float v; int p;
    if (mode == 0) {
      int b = i >> 5, l = i & 31;
      int tok = (m < NC) ? cand[b * (NC * NL) + m * NL + l]
                         : clicked[b * (NH * NL) + (m - NC) * NL + l];
      v = s2src[tok]; p = tok;
    } else {
      if (i < N) { v = s2src[i]; p = i; } else { v = __builtin_inff(); p = 0; }
    }
    sval[i] = v; spay[i] = p;
  }
  __syncthreads();
  for (int k = 2; k <= SZ; k <<= 1) {
    for (int j = k >> 1; j > 0; j >>= 1) {
      for (int i = tid; i < SZ; i += 1024) {
        int ixj = i ^ j;
        if (ixj > i) {
          bool asc = ((i & k) == 0);
          float a = sval[i], bb = sval[ixj];
          bool sw = asc ? (a > bb) : (a < bb);
          if (sw) {
            sval[i] = bb; sval[ixj] = a;
            int t = spay[i]; spay[i] = spay[ixj]; spay[ixj] = t;
          }
        }
      }
      __syncthreads();
    }
  }
  for (int i = tid; i < Epad; i += 1024) {
    float v = sval[i];
    if (i < N) s2s_g[i] = v;
    E1_g[i] = (i < N) ? expf(v) : 0.f;
    E02_g[i] = (i < N) ? expf(0.2f * v) : 0.f;
    perm_g[i] = spay[i];
  }
}

// ---------------------------------------------------------------------------
// Chunked weighted prefix accumulation at granularity 16 (local prefixes).
// ---------------------------------------------------------------------------
__global__ __launch_bounds__(320) void k_scan(const float* __restrict__ base,
                                              const int* __restrict__ perm,
                                              const float* __restrict__ E1,
                                              const float* __restrict__ E02,
                                              float* __restrict__ C1, float* __restrict__ C02,
                                              int Epad, int cstride) {
  const int g = blockIdx.y, kc = blockIdx.x;
  const int col = threadIdx.x;
  const int* perm_g = perm + (size_t)g * Epad;
  const float* E1_g = E1 + (size_t)g * Epad;
  const float* E02_g = E02 + (size_t)g * Epad;
  float* C1_g = C1 + (size_t)g * cstride * CW;
  float* C02_g = C02 + (size_t)g * cstride * CW;
  const bool datacol = (col < DD);
  const float wden = (col == DD) ? 1.f : 0.f;
  float acc1 = 0.f, acc2 = 0.f;
  const int k0 = kc * 256;
#pragma unroll 8
  for (int kk = 0; kk < 256; ++kk) {
    int k = k0 + kk;
    int tok = perm_g[k];
    float e1 = E1_g[k], e02 = E02_g[k];
    float w = datacol ? base[(size_t)tok * DD + col] : wden;
    acc1 = fmaf(e1, w, acc1);
    acc2 = fmaf(e02, w, acc2);
    if ((kk & 15) == 15) {
      int t = (k + 1) >> 4;
      if (col < CW) { C1_g[(size_t)t * CW + col] = acc1; C02_g[(size_t)t * CW + col] = acc2; }
    }
  }
}

// Fix-up: local -> global prefixes; row 0 := 0.
__global__ __launch_bounds__(320) void k_fix(float* __restrict__ C1, float* __restrict__ C02,
                                             int nkc, int cstride) {
  const int g = blockIdx.x, col = threadIdx.x;
  if (col >= CW) return;
  float* C1_g = C1 + (size_t)g * cstride * CW;
  float* C02_g = C02 + (size_t)g * cstride * CW;
  C1_g[col] = 0.f; C02_g[col] = 0.f;
  float off1 = 0.f, off2 = 0.f;
  for (int kc = 0; kc < nkc; ++kc) {
    float l1 = 0.f, l2 = 0.f;
    for (int tl = 1; tl <= 16; ++tl) {
      size_t idx = (size_t)(kc * 16 + tl) * CW + col;
      float v1 = C1_g[idx], v2 = C02_g[idx];
      C1_g[idx] = v1 + off1; C02_g[idx] = v2 + off2;
      if (tl == 16) { l1 = v1; l2 = v2; }
    }
    off1 += l1; off2 += l2;
  }
}

// ---------------------------------------------------------------------------
// GAT row construction: one wave computes 2 rows; sorted s2 staged in LDS.
// Writes post-elu g rows as bf16 with stride GSTR (cols 300..319 zeroed).
// ---------------------------------------------------------------------------
__global__ __launch_bounds__(256) void k_rows(
    const int* __restrict__ cand, const int* __restrict__ clicked,
    const float* __restrict__ base, const float* __restrict__ s1src,
    const float* __restrict__ s2s, const int* __restrict__ perm,
    const float* __restrict__ E1, const float* __restrict__ E02,
    const float* __restrict__ C1, const float* __restrict__ C02,
    __hip_bfloat16* __restrict__ gout,
    int mode, int N, int NT, int Epad) {
  __shared__ float s2l[NUSR];
  const int m = blockIdx.y, chunk = blockIdx.x;
  const int tid = threadIdx.x;
  const int wave = tid >> 6, lane = tid & 63;
  const float* s2s_m = s2s + (size_t)m * N;
  const int* perm_m = perm + (size_t)m * Epad;
  const float* E1_m = E1 + (size_t)m * Epad;
  const float* E02_m = E02 + (size_t)m * Epad;
  const float* C1_m = C1 + (size_t)m * (NT + 1) * CW;
  const float* C02_m = C02 + (size_t)m * (NT + 1) * CW;
  for (int i = tid; i < N; i += 256) s2l[i] = s2s_m[i];
  __syncthreads();
  const float T1den = C1_m[(size_t)NT * CW + DD];

  for (int sub = 0; sub < 2; ++sub) {
    const int r = chunk * 8 + wave * 2 + sub;
    if (r >= N) continue;
    int tok;
    if (mode == 0) {
      int b = r >> 5, l = r & 31;
      tok = (m < NC) ? cand[b * (NC * NL) + m * NL + l]
                     : clicked[b * (NH * NL) + (m - NC) * NL + l];
    } else {
      tok = r;
    }
    float s1 = s1src[tok];
    float es1 = expf(s1), es02 = expf(0.2f * s1);
    float tau = -s1;
    int lo = 0, hi = N;
    while (lo < hi) { int mid = (lo + hi) >> 1; if (s2l[mid] <= tau) lo = mid + 1; else hi = mid; }
    const int ki = lo, t = ki >> 4, nr = ki & 15, kr0 = t << 4;
    float rd1 = 0.f, rd2 = 0.f;
    float rv1[5] = {0, 0, 0, 0, 0}, rv2[5] = {0, 0, 0, 0, 0};
    for (int rr = 0; rr < nr; ++rr) {
      int tk = perm_m[kr0 + rr];
      float e1 = E1_m[kr0 + rr], e02 = E02_m[kr0 + rr];
      rd1 += e1; rd2 += e02;
      const float* wr = base + (size_t)tk * DD;
#pragma unroll
      for (int c = 0; c < 5; ++c) {
        int d = lane + 64 * c;
        if (d < DD) { float w = wr[d]; rv1[c] = fmaf(e1, w, rv1[c]); rv2[c] = fmaf(e02, w, rv2[c]); }
      }
    }
    float den = es1 * (T1den - C1_m[(size_t)t * CW + DD] - rd1) +
                es02 * (C02_m[(size_t)t * CW + DD] + rd2);
    float rden = 1.f / den;
    __hip_bfloat16* gr = gout + ((size_t)m * N + r) * GSTR;
#pragma unroll
    for (int c = 0; c < 5; ++c) {
      int d = lane + 64 * c;
      float ev = 0.f;
      if (d < DD) {
        float num = es1 * (C1_m[(size_t)NT * CW + d] - C1_m[(size_t)t * CW + d] - rv1[c]) +
                    es02 * (C02_m[(size_t)t * CW + d] + rv2[c]);
        float gg = num * rden;
        ev = (gg > 0.f) ? gg : expm1f(gg);
      }
      gr[d] = __float2bfloat16(ev);
    }
  }
}

// ---------------------------------------------------------------------------
// Pack lin_w [Q,300] fp32 -> bf16 B-fragments for mfma_f32_16x16x32_bf16:
// entry e = (nt*KTILES+kt)*64 + lane; element j: B[k=kt*32+(lane>>4)*8+j]
// [n=nt*16+(lane&15)] = lin_w[n][k] (0 outside). Lane-contiguous dwordx4 loads.
// ---------------------------------------------------------------------------
__global__ __launch_bounds__(256) void k_packB(const float* __restrict__ lw,
                                               __hip_bfloat16* __restrict__ Bp) {
  int e = blockIdx.x * 256 + threadIdx.x;
  if (e >= BPELT) return;
  int lane = e & 63, kt = (e >> 6) % KTILES, nt = (e >> 6) / KTILES;
  int n = nt * 16 + (lane & 15);
  int k0 = kt * 32 + (lane >> 4) * 8;
  __hip_bfloat16 vals[8];
#pragma unroll
  for (int j = 0; j < 8; ++j) {
    int k = k0 + j;
    float v = (n < QQ && k < DD) ? lw[(size_t)n * DD + k] : 0.f;
    vals[j] = __float2bfloat16(v);
  }
  *(bf16x8*)(Bp + (size_t)e * 8) = *(const bf16x8*)vals;
}

// ---------------------------------------------------------------------------
// logits[r] = tanh(g[r,:] @ lin_w.T + b) . query  via bf16 MFMA.
// Block = 64 rows (4 waves x 16). A-frags held in regs across all 13 N-tiles.
// ---------------------------------------------------------------------------
__global__ __launch_bounds__(256) void k_logits(
    const __hip_bfloat16* __restrict__ g, const __hip_bfloat16* __restrict__ Bp,
    const float* __restrict__ lin_b, const float* __restrict__ query,
    float* __restrict__ logits) {
  const int tid = threadIdx.x;
  const int wave = tid >> 6, lane = tid & 63;
  const int quad = lane >> 4, l16 = lane & 15;
  const int rbase = blockIdx.x * 64 + wave * 16;
  // A operand: lane holds row rbase+l16, k = kt*32 + quad*8 + j
  const __hip_bfloat16* grow = g + (size_t)(rbase + l16) * GSTR + quad * 8;
  bf16x8 afr[KTILES];
#pragma unroll
  for (int kt = 0; kt < KTILES; ++kt)
    afr[kt] = *(const bf16x8*)(grow + kt * 32);
  float part[4] = {0.f, 0.f, 0.f, 0.f};
  for (int nt = 0; nt < NTILES_N; ++nt) {
    f32x4 acc = {0.f, 0.f, 0.f, 0.f};
    const bf16x8* bp = (const bf16x8*)Bp + (size_t)nt * KTILES * 64 + lane;
#pragma unroll
    for (int kt = 0; kt < KTILES; ++kt)
      acc = __builtin_amdgcn_mfma_f32_16x16x32_bf16(afr[kt], bp[kt * 64], acc, 0, 0, 0);
    const int n = nt * 16 + l16;             // this lane's output column
    const float qv = (n < QQ) ? query[n] : 0.f;
    const float bv = (n < QQ) ? lin_b[n] : 0.f;
#pragma unroll
    for (int r = 0; r < 4; ++r)              // acc[r] -> row quad*4+r, col n
      part[r] = fmaf(tanhf(acc[r] + bv), qv, part[r]);
  }
#pragma unroll
  for (int r = 0; r < 4; ++r) {
    float p = part[r];
    p += __shfl_xor(p, 1, 64); p += __shfl_xor(p, 2, 64);
    p += __shfl_xor(p, 4, 64); p += __shfl_xor(p, 8, 64);
    if (l16 == 0) logits[rbase + quad * 4 + r] = p;
  }
}

// ---------------------------------------------------------------------------
// News additive attention: softmax over 32 logits + weighted sum of g rows.
// ---------------------------------------------------------------------------
__global__ __launch_bounds__(192) void k_attn_lite(
    const __hip_bfloat16* __restrict__ g, const float* __restrict__ logits,
    float* __restrict__ cand_enc, float* __restrict__ clicked_enc) {
  __shared__ float wgt[32];
  const int b = blockIdx.x, m = blockIdx.y, tid = threadIdx.x;
  if (tid < 32) {
    float lg = logits[(size_t)m * NROW + b * NL + tid];
    float mx = lg;
    for (int o = 16; o; o >>= 1) mx = fmaxf(mx, __shfl_xor(mx, o, 32));
    float e = expf(lg - mx);
    float sm = e;
    for (int o = 16; o; o >>= 1) sm += __shfl_xor(sm, o, 32);
    wgt[tid] = e / sm;
  }
  __syncthreads();
  if (tid < 150) {
    const __hip_bfloat16* base = g + (size_t)(m * NROW + b * NL) * GSTR;
    float a0 = 0.f, a1 = 0.f;
#pragma unroll 8
    for (int l = 0; l < 32; ++l) {
      unsigned u = *(const unsigned*)(base + (size_t)l * GSTR + 2 * tid);
      float w = wgt[l];
      a0 = fmaf(w, __uint_as_float(u << 16), a0);
      a1 = fmaf(w, __uint_as_float(u & 0xffff0000u), a1);
    }
    float* outp = (m < NC) ? (cand_enc + ((size_t)b * NC + m) * DD)
                           : (clicked_enc + ((size_t)b * NH + (m - NC)) * DD);
    outp[2 * tid] = a0; outp[2 * tid + 1] = a1;
  }
}

// User additive attention: softmax over 50 logits + weighted sum.
__global__ __launch_bounds__(192) void k_attn_user_lite(
    const __hip_bfloat16* __restrict__ g, const float* __restrict__ logits,
    float* __restrict__ user_enc) {
  __shared__ float wgt[64];
  const int b = blockIdx.x, tid = threadIdx.x;
  if (tid < 64) {
    float lg = (tid < NH) ? logits[(size_t)b * NH + tid] : -__builtin_inff();
    float mx = lg;
    for (int o = 32; o; o >>= 1) mx = fmaxf(mx, __shfl_xor(mx, o, 64));
    float e = (tid < NH) ? expf(lg - mx) : 0.f;
    float sm = e;
    for (int o = 32; o; o >>= 1) sm += __shfl_xor(sm, o, 64);
    wgt[tid] = e / sm;
  }
  __syncthreads();
  if (tid < 150) {
    const __hip_bfloat16* base = g + (size_t)(b * NH) * GSTR;
    float a0 = 0.f, a1 = 0.f;
#pragma unroll 10
    for (int h = 0; h < NH; ++h) {
      unsigned u = *(const unsigned*)(base + (size_t)h * GSTR + 2 * tid);
      float w = wgt[h];
      a0 = fmaf(w, __uint_as_float(u << 16), a0);
      a1 = fmaf(w, __uint_as_float(u & 0xffff0000u), a1);
    }
    user_enc[(size_t)b * DD + 2 * tid] = a0;
    user_enc[(size_t)b * DD + 2 * tid + 1] = a1;
  }
}

// Final: out[b,c] = cand_enc[b,c,:]·user_enc[b,:]
__global__ __launch_bounds__(64) void k_dot(const float* __restrict__ cand_enc,
                                            const float* __restrict__ user_enc,
                                            float* __restrict__ out) {
  const int bc = blockIdx.x, b = bc / NC, lane = threadIdx.x;
  const float* cp = cand_enc + (size_t)bc * DD;
  const float* up = user_enc + (size_t)b * DD;
  float s = 0.f;
  for (int d = lane; d < DD; d += 64) s = fmaf(cp[d], up[d], s);
  for (int o = 32; o; o >>= 1) s += __shfl_xor(s, o, 64);
  if (lane == 0) out[bc] = s;
}

// ---------------------------------------------------------------------------
extern "C" void kernel_launch(void* const* d_in, const int* in_sizes, int n_in,
                              void* d_out, int out_size, void* d_ws, size_t ws_size,
                              hipStream_t stream) {
  const int* cand = (const int*)d_in[0];
  const int* clicked = (const int*)d_in[1];
  const float* emb = (const float*)d_in[2];
  const float* news_W = (const float*)d_in[3];
  const float* news_a = (const float*)d_in[4];
  const float* news_lw = (const float*)d_in[5];
  const float* news_lb = (const float*)d_in[6];
  const float* news_q = (const float*)d_in[7];
  const float* user_W = (const float*)d_in[8];
  const float* user_a = (const float*)d_in[9];
  const float* user_lw = (const float*)d_in[10];
  const float* user_lb = (const float*)d_in[11];
  const float* user_q = (const float*)d_in[12];
  float* out = (float*)d_out;

  float* W = (float*)d_ws;
  size_t o = 0;
  auto nxt = [&](size_t n) { size_t c = o; o += (n + 63) & ~(size_t)63; return c; };
  float* EW = W + nxt((size_t)NVOC * DD);
  float* s1v = W + nxt(NVOC);
  float* s2v = W + nxt(NVOC);
  float* s2s = W + nxt((size_t)NGAT * NROW);
  int* perm = (int*)(W + nxt((size_t)NGAT * NROW));
  float* E1 = W + nxt((size_t)NGAT * NROW);
  float* E02 = W + nxt((size_t)NGAT * NROW);
  float* C1 = W + nxt((size_t)NGAT * (NT_NEWS + 1) * CW);
  float* C02 = W + nxt((size_t)NGAT * (NT_NEWS + 1) * CW);
  float* cand_enc = W + nxt((size_t)BN_B * NC * DD);
  float* clicked_enc = W + nxt((size_t)BN_B * NH * DD);
  float* WhU = W + nxt((size_t)NUSR * DD);
  float* s1u = W + nxt(NUSR);
  float* s2u = W + nxt(NUSR);
  float* s2sU = W + nxt(NUSR_PAD);
  int* permU = (int*)(W + nxt(NUSR_PAD));
  float* E1U = W + nxt(NUSR_PAD);
  float* E02U = W + nxt(NUSR_PAD);
  float* C1U = W + nxt((size_t)(NT_USER + 1) * CW);
  float* C02U = W + nxt((size_t)(NT_USER + 1) * CW);
  float* user_enc = W + nxt((size_t)BN_B * DD);
  float* logitsN = W + nxt((size_t)NGAT * NROW);
  float* logitsU = W + nxt(NUSR);
  __hip_bfloat16* BpN = (__hip_bfloat16*)(W + nxt((size_t)BPELT * 8 / 2));
  __hip_bfloat16* BpU = (__hip_bfloat16*)(W + nxt((size_t)BPELT * 8 / 2));
  __hip_bfloat16* g_news = (__hip_bfloat16*)(W + nxt((size_t)NGAT * NROW * GSTR / 2));
  __hip_bfloat16* g_user = (__hip_bfloat16*)(W + nxt((size_t)NUSR * GSTR / 2));

  const int packgrid = (BPELT + 255) / 256;

  // 1. EW = emb @ news_W
  k_gemm300<<<dim3((NVOC + 63) / 64, 5), 256, 0, stream>>>(emb, news_W, EW, NVOC);
  // 2. per-vocab attention scalars
  k_sv<<<(NVOC + 3) / 4, 256, 0, stream>>>(EW, news_a, s1v, s2v, NVOC);
  // 3. sort s2 per news GAT + exp tables
  k_sort<<<NGAT, 1024, 0, stream>>>(cand, clicked, s2v, s2s, perm, E1, E02, 0, NROW, NROW, NROW);
  // 4-5. coarse weighted prefix sums
  k_scan<<<dim3(8, NGAT), 320, 0, stream>>>(EW, perm, E1, E02, C1, C02, NROW, NT_NEWS + 1);
  k_fix<<<NGAT, 320, 0, stream>>>(C1, C02, 8, NT_NEWS + 1);
  // 6. GAT rows -> g_news (bf16, stride 320)
  k_rows<<<dim3(NROW / 8, NGAT), 256, 0, stream>>>(cand, clicked, EW, s1v, s2s, perm, E1, E02,
                                                   C1, C02, g_news, 0, NROW, NT_NEWS, NROW);
  // 7. MFMA logits + lite attention -> cand/clicked encodings
  k_packB<<<packgrid, 256, 0, stream>>>(news_lw, BpN);
  k_logits<<<NGAT * NROW / 64, 256, 0, stream>>>(g_news, BpN, news_lb, news_q, logitsN);
  k_attn_lite<<<dim3(BN_B, NGAT), 192, 0, stream>>>(g_news, logitsN, cand_enc, clicked_enc);
  // 8-12. user GAT over clicked encodings
  k_gemm300<<<dim3(NUSR / 64, 5), 256, 0, stream>>>(clicked_enc, user_W, WhU, NUSR);
  k_sv<<<NUSR / 4, 256, 0, stream>>>(WhU, user_a, s1u, s2u, NUSR);
  k_sort<<<1, 1024, 0, stream>>>(nullptr, nullptr, s2u, s2sU, permU, E1U, E02U, 1, NUSR, 4096, NUSR_PAD);
  k_scan<<<dim3(13, 1), 320, 0, stream>>>(WhU, permU, E1U, E02U, C1U, C02U, NUSR_PAD, NT_USER + 1);
  k_fix<<<1, 320, 0, stream>>>(C1U, C02U, 13, NT_USER + 1);
  k_rows<<<dim3((NUSR + 7) / 8, 1), 256, 0, stream>>>(nullptr, nullptr, WhU, s1u, s2sU, permU,
                                                      E1U, E02U, C1U, C02U, g_user,
                                                      1, NUSR, NT_USER, NUSR_PAD);
  // 13. user logits + attention
  k_packB<<<packgrid, 256, 0, stream>>>(user_lw, BpU);
  k_logits<<<NUSR / 64, 256, 0, stream>>>(g_user, BpU, user_lb, user_q, logitsU);
  k_attn_user_lite<<<BN_B, 192, 0, stream>>>(g_user, logitsU, user_enc);
  // 14. click score
  k_dot<<<BN_B * NC, 64, 0, stream>>>(cand_enc, user_enc, out);
}

// Round 4
// 830.675 us; speedup vs baseline: 1.6847x; 1.1174x over previous
//
#include <hip/hip_runtime.h>
#include <hip/hip_bf16.h>

// Problem constants
#define BN_B 64
#define NC 5
#define NH 50
#define NL 32
#define DD 300
#define QQ 200
#define NVOC 50000
#define NGAT 55          // 5 candidate + 50 clicked news GATs
#define NROW 2048        // rows per news GAT (B*L)
#define NUSR 3200        // rows user GAT (B*H)
#define NUSR_PAD 3328    // 13*256
#define CW 304           // prefix array row width (300 data + col300 = denominator)
#define NT_NEWS 128      // 2048/16
#define NT_USER 208      // 3328/16
#define GSTR 320         // padded g row stride (10 K-tiles of 32 for MFMA)
#define NTILES_N 13      // ceil(200/16)
#define KTILES 10        // 320/32
#define BPELT (NTILES_N * KTILES * 64)  // B-fragment entries (x8 bf16 each)
// W-GEMM (split bf16 MFMA) tiling: N=304 -> 19 n-tiles, K=320 -> 10 k-tiles
#define WNT 19
#define WKT 10
#define WPELT (WNT * WKT * 64)

typedef short bf16x8 __attribute__((ext_vector_type(8)));
typedef float f32x4 __attribute__((ext_vector_type(4)));

// ---------------------------------------------------------------------------
// Pack W [300,300] fp32 -> split bf16 (hi/lo) B-fragments for 16x16x32 MFMA.
// Fragment entry e = (kt*WNT + nt)*64 + lane; element j:
//   B[k = kt*32 + (lane>>4)*8 + j][n = nt*16 + (lane&15)]  (0 outside).
// ---------------------------------------------------------------------------
__global__ __launch_bounds__(256) void k_packW(const float* __restrict__ Wm,
                                               __hip_bfloat16* __restrict__ Bhi,
                                               __hip_bfloat16* __restrict__ Blo) {
  int e = blockIdx.x * 256 + threadIdx.x;
  if (e >= WPELT) return;
  int lane = e & 63, nt = (e >> 6) % WNT, kt = (e >> 6) / WNT;
  int n = nt * 16 + (lane & 15);
  int k0 = kt * 32 + (lane >> 4) * 8;
  __hip_bfloat16 hv[8], lv[8];
#pragma unroll
  for (int j = 0; j < 8; ++j) {
    int k = k0 + j;
    float v = (k < DD && n < DD) ? Wm[(size_t)k * DD + n] : 0.f;
    __hip_bfloat16 h = __float2bfloat16(v);
    hv[j] = h;
    lv[j] = __float2bfloat16(v - __bfloat162float(h));
  }
  *(bf16x8*)(Bhi + (size_t)e * 8) = *(const bf16x8*)hv;
  *(bf16x8*)(Blo + (size_t)e * 8) = *(const bf16x8*)lv;
}

// ---------------------------------------------------------------------------
// C[M,300] = A[M,300] @ W[300,300] via split-bf16 MFMA (3 products ~ fp32).
// 4 waves/block, 16 rows/wave, 19 n-tile accumulators across the K-loop.
// No LDS: B-fragments stream from L2; A converted fp32->hi/lo in registers.
// ---------------------------------------------------------------------------
__global__ __launch_bounds__(256) void k_gemm_mfma(const float* __restrict__ A,
                                                   const __hip_bfloat16* __restrict__ Bhi,
                                                   const __hip_bfloat16* __restrict__ Blo,
                                                   float* __restrict__ C, int M) {
  const int tid = threadIdx.x;
  const int wave = tid >> 6, lane = tid & 63;
  const int quad = lane >> 4, l16 = lane & 15;
  const int rowA = blockIdx.x * 64 + wave * 16 + l16;   // row this lane's A-frag holds
  const float* ar = A + (size_t)rowA * DD;
  f32x4 acc[WNT];
#pragma unroll
  for (int nt = 0; nt < WNT; ++nt) acc[nt] = (f32x4){0.f, 0.f, 0.f, 0.f};

  for (int kt = 0; kt < WKT; ++kt) {
    const int k0 = kt * 32 + quad * 8;
    float av[8];
    if (rowA < M && k0 + 8 <= DD) {
      float4 v0 = *(const float4*)(ar + k0);
      float4 v1 = *(const float4*)(ar + k0 + 4);
      av[0] = v0.x; av[1] = v0.y; av[2] = v0.z; av[3] = v0.w;
      av[4] = v1.x; av[5] = v1.y; av[6] = v1.z; av[7] = v1.w;
    } else {
#pragma unroll
      for (int j = 0; j < 8; ++j) {
        int k = k0 + j;
        av[j] = (rowA < M && k < DD) ? ar[k] : 0.f;
      }
    }
    __hip_bfloat16 hv[8], lv[8];
#pragma unroll
    for (int j = 0; j < 8; ++j) {
      __hip_bfloat16 h = __float2bfloat16(av[j]);
      hv[j] = h;
      lv[j] = __float2bfloat16(av[j] - __bfloat162float(h));
    }
    const bf16x8 ah = *(const bf16x8*)hv;
    const bf16x8 al = *(const bf16x8*)lv;
    const bf16x8* bh = (const bf16x8*)Bhi + (size_t)(kt * WNT) * 64 + lane;
    const bf16x8* bl = (const bf16x8*)Blo + (size_t)(kt * WNT) * 64 + lane;
#pragma unroll
    for (int nt = 0; nt < WNT; ++nt) {
      bf16x8 bhf = bh[nt * 64], blf = bl[nt * 64];
      acc[nt] = __builtin_amdgcn_mfma_f32_16x16x32_bf16(ah, bhf, acc[nt], 0, 0, 0);
      acc[nt] = __builtin_amdgcn_mfma_f32_16x16x32_bf16(al, bhf, acc[nt], 0, 0, 0);
      acc[nt] = __builtin_amdgcn_mfma_f32_16x16x32_bf16(ah, blf, acc[nt], 0, 0, 0);
    }
  }
  // D layout: row = quad*4 + r (within wave's 16), col = nt*16 + l16
  const int mbase = blockIdx.x * 64 + wave * 16 + quad * 4;
#pragma unroll
  for (int nt = 0; nt < WNT; ++nt) {
    int n = nt * 16 + l16;
    if (n < DD) {
#pragma unroll
      for (int r = 0; r < 4; ++r) {
        int mr = mbase + r;
        if (mr < M) C[(size_t)mr * DD + n] = acc[nt][r];
      }
    }
  }
}

// ---------------------------------------------------------------------------
// s1/s2 per row
// ---------------------------------------------------------------------------
__global__ __launch_bounds__(256) void k_sv(const float* __restrict__ Wh,
                                            const float* __restrict__ avec,
                                            float* __restrict__ s1, float* __restrict__ s2, int M) {
  int row = blockIdx.x * 4 + (threadIdx.x >> 6);
  int lane = threadIdx.x & 63;
  if (row >= M) return;
  const float* wr = Wh + (size_t)row * DD;
  float p1 = 0.f, p2 = 0.f;
  for (int d = lane; d < DD; d += 64) {
    float w = wr[d];
    p1 = fmaf(w, avec[d], p1);
    p2 = fmaf(w, avec[DD + d], p2);
  }
  for (int o = 32; o; o >>= 1) { p1 += __shfl_xor(p1, o, 64); p2 += __shfl_xor(p2, o, 64); }
  if (lane == 0) { s1[row] = p1; s2[row] = p2; }
}

// ---------------------------------------------------------------------------
// Bitonic sort of s2 values + exp tables
// ---------------------------------------------------------------------------
__global__ __launch_bounds__(1024) void k_sort(const int* __restrict__ cand,
                                               const int* __restrict__ clicked,
                                               const float* __restrict__ s2src,
                                               float* __restrict__ s2s, int* __restrict__ perm,
                                               float* __restrict__ E1, float* __restrict__ E02,
                                               int mode, int N, int SZ, int Epad) {
  __shared__ float sval[4096];
  __shared__ int spay[4096];
  const int m = blockIdx.x;
  const int tid = threadIdx.x;
  float* s2s_g = s2s + (size_t)m * N;
  int* perm_g = perm + (size_t)m * Epad;
  float* E1_g = E1 + (size_t)m * Epad;
  float* E02_g = E02 + (size_t)m * Epad;

  for (int i = tid; i < SZ; i += 1024) {
    float v; int p;
    if (mode == 0) {
      int b = i >> 5, l = i & 31;
      int tok = (m < NC) ? cand[b * (NC * NL) + m * NL + l]
                         : clicked[b * (NH * NL) + (m - NC) * NL + l];
      v = s2src[tok]; p = tok;
    } else {
      if (i < N) { v = s2src[i]; p = i; } else { v = __builtin_inff(); p = 0; }
    }
    sval[i] = v; spay[i] = p;
  }
  __syncthreads();
  for (int k = 2; k <= SZ; k <<= 1) {
    for (int j = k >> 1; j > 0; j >>= 1) {
      for (int i = tid; i < SZ; i += 1024) {
        int ixj = i ^ j;
        if (ixj > i) {
          bool asc = ((i & k) == 0);
          float a = sval[i], bb = sval[ixj];
          bool sw = asc ? (a > bb) : (a < bb);
          if (sw) {
            sval[i] = bb; sval[ixj] = a;
            int t = spay[i]; spay[i] = spay[ixj]; spay[ixj] = t;
          }
        }
      }
      __syncthreads();
    }
  }
  for (int i = tid; i < Epad; i += 1024) {
    float v = sval[i];
    if (i < N) s2s_g[i] = v;
    E1_g[i] = (i < N) ? expf(v) : 0.f;
    E02_g[i] = (i < N) ? expf(0.2f * v) : 0.f;
    perm_g[i] = spay[i];
  }
}

// ---------------------------------------------------------------------------
// Chunked weighted prefix accumulation at granularity 16 (local prefixes).
// ---------------------------------------------------------------------------
__global__ __launch_bounds__(320) void k_scan(const float* __restrict__ base,
                                              const int* __restrict__ perm,
                                              const float* __restrict__ E1,
                                              const float* __restrict__ E02,
                                              float* __restrict__ C1, float* __restrict__ C02,
                                              int Epad, int cstride) {
  const int g = blockIdx.y, kc = blockIdx.x;
  const int col = threadIdx.x;
  const int* perm_g = perm + (size_t)g * Epad;
  const float* E1_g = E1 + (size_t)g * Epad;
  const float* E02_g = E02 + (size_t)g * Epad;
  float* C1_g = C1 + (size_t)g * cstride * CW;
  float* C02_g = C02 + (size_t)g * cstride * CW;
  const bool datacol = (col < DD);
  const float wden = (col == DD) ? 1.f : 0.f;
  float acc1 = 0.f, acc2 = 0.f;
  const int k0 = kc * 256;
#pragma unroll 8
  for (int kk = 0; kk < 256; ++kk) {
    int k = k0 + kk;
    int tok = perm_g[k];
    float e1 = E1_g[k], e02 = E02_g[k];
    float w = datacol ? base[(size_t)tok * DD + col] : wden;
    acc1 = fmaf(e1, w, acc1);
    acc2 = fmaf(e02, w, acc2);
    if ((kk & 15) == 15) {
      int t = (k + 1) >> 4;
      if (col < CW) { C1_g[(size_t)t * CW + col] = acc1; C02_g[(size_t)t * CW + col] = acc2; }
    }
  }
}

// Fix-up: local -> global prefixes; row 0 := 0.
__global__ __launch_bounds__(320) void k_fix(float* __restrict__ C1, float* __restrict__ C02,
                                             int nkc, int cstride) {
  const int g = blockIdx.x, col = threadIdx.x;
  if (col >= CW) return;
  float* C1_g = C1 + (size_t)g * cstride * CW;
  float* C02_g = C02 + (size_t)g * cstride * CW;
  C1_g[col] = 0.f; C02_g[col] = 0.f;
  float off1 = 0.f, off2 = 0.f;
  for (int kc = 0; kc < nkc; ++kc) {
    float l1 = 0.f, l2 = 0.f;
    for (int tl = 1; tl <= 16; ++tl) {
      size_t idx = (size_t)(kc * 16 + tl) * CW + col;
      float v1 = C1_g[idx], v2 = C02_g[idx];
      C1_g[idx] = v1 + off1; C02_g[idx] = v2 + off2;
      if (tl == 16) { l1 = v1; l2 = v2; }
    }
    off1 += l1; off2 += l2;
  }
}

// ---------------------------------------------------------------------------
// GAT row construction: one wave computes 2 rows; sorted s2 staged in LDS.
// Writes post-elu g rows as bf16 with stride GSTR (cols 300..319 zeroed).
// ---------------------------------------------------------------------------
__global__ __launch_bounds__(256) void k_rows(
    const int* __restrict__ cand, const int* __restrict__ clicked,
    const float* __restrict__ base, const float* __restrict__ s1src,
    const float* __restrict__ s2s, const int* __restrict__ perm,
    const float* __restrict__ E1, const float* __restrict__ E02,
    const float* __restrict__ C1, const float* __restrict__ C02,
    __hip_bfloat16* __restrict__ gout,
    int mode, int N, int NT, int Epad) {
  __shared__ float s2l[NUSR];
  const int m = blockIdx.y, chunk = blockIdx.x;
  const int tid = threadIdx.x;
  const int wave = tid >> 6, lane = tid & 63;
  const float* s2s_m = s2s + (size_t)m * N;
  const int* perm_m = perm + (size_t)m * Epad;
  const float* E1_m = E1 + (size_t)m * Epad;
  const float* E02_m = E02 + (size_t)m * Epad;
  const float* C1_m = C1 + (size_t)m * (NT + 1) * CW;
  const float* C02_m = C02 + (size_t)m * (NT + 1) * CW;
  for (int i = tid; i < N; i += 256) s2l[i] = s2s_m[i];
  __syncthreads();
  const float T1den = C1_m[(size_t)NT * CW + DD];

  for (int sub = 0; sub < 2; ++sub) {
    const int r = chunk * 8 + wave * 2 + sub;
    if (r >= N) continue;
    int tok;
    if (mode == 0) {
      int b = r >> 5, l = r & 31;
      tok = (m < NC) ? cand[b * (NC * NL) + m * NL + l]
                     : clicked[b * (NH * NL) + (m - NC) * NL + l];
    } else {
      tok = r;
    }
    float s1 = s1src[tok];
    float es1 = expf(s1), es02 = expf(0.2f * s1);
    float tau = -s1;
    int lo = 0, hi = N;
    while (lo < hi) { int mid = (lo + hi) >> 1; if (s2l[mid] <= tau) lo = mid + 1; else hi = mid; }
    const int ki = lo, t = ki >> 4, nr = ki & 15, kr0 = t << 4;
    float rd1 = 0.f, rd2 = 0.f;
    float rv1[5] = {0, 0, 0, 0, 0}, rv2[5] = {0, 0, 0, 0, 0};
    for (int rr = 0; rr < nr; ++rr) {
      int tk = perm_m[kr0 + rr];
      float e1 = E1_m[kr0 + rr], e02 = E02_m[kr0 + rr];
      rd1 += e1; rd2 += e02;
      const float* wr = base + (size_t)tk * DD;
#pragma unroll
      for (int c = 0; c < 5; ++c) {
        int d = lane + 64 * c;
        if (d < DD) { float w = wr[d]; rv1[c] = fmaf(e1, w, rv1[c]); rv2[c] = fmaf(e02, w, rv2[c]); }
      }
    }
    float den = es1 * (T1den - C1_m[(size_t)t * CW + DD] - rd1) +
                es02 * (C02_m[(size_t)t * CW + DD] + rd2);
    float rden = 1.f / den;
    __hip_bfloat16* gr = gout + ((size_t)m * N + r) * GSTR;
#pragma unroll
    for (int c = 0; c < 5; ++c) {
      int d = lane + 64 * c;
      float ev = 0.f;
      if (d < DD) {
        float num = es1 * (C1_m[(size_t)NT * CW + d] - C1_m[(size_t)t * CW + d] - rv1[c]) +
                    es02 * (C02_m[(size_t)t * CW + d] + rv2[c]);
        float gg = num * rden;
        ev = (gg > 0.f) ? gg : expm1f(gg);
      }
      gr[d] = __float2bfloat16(ev);
    }
  }
}

// ---------------------------------------------------------------------------
// Pack lin_w [Q,300] fp32 -> bf16 B-fragments for mfma_f32_16x16x32_bf16.
// ---------------------------------------------------------------------------
__global__ __launch_bounds__(256) void k_packB(const float* __restrict__ lw,
                                               __hip_bfloat16* __restrict__ Bp) {
  int e = blockIdx.x * 256 + threadIdx.x;
  if (e >= BPELT) return;
  int lane = e & 63, kt = (e >> 6) % KTILES, nt = (e >> 6) / KTILES;
  int n = nt * 16 + (lane & 15);
  int k0 = kt * 32 + (lane >> 4) * 8;
  __hip_bfloat16 vals[8];
#pragma unroll
  for (int j = 0; j < 8; ++j) {
    int k = k0 + j;
    float v = (n < QQ && k < DD) ? lw[(size_t)n * DD + k] : 0.f;
    vals[j] = __float2bfloat16(v);
  }
  *(bf16x8*)(Bp + (size_t)e * 8) = *(const bf16x8*)vals;
}

// ---------------------------------------------------------------------------
// logits[r] = tanh(g[r,:] @ lin_w.T + b) . query  via bf16 MFMA.
// ---------------------------------------------------------------------------
__global__ __launch_bounds__(256) void k_logits(
    const __hip_bfloat16* __restrict__ g, const __hip_bfloat16* __restrict__ Bp,
    const float* __restrict__ lin_b, const float* __restrict__ query,
    float* __restrict__ logits) {
  const int tid = threadIdx.x;
  const int wave = tid >> 6, lane = tid & 63;
  const int quad = lane >> 4, l16 = lane & 15;
  const int rbase = blockIdx.x * 64 + wave * 16;
  const __hip_bfloat16* grow = g + (size_t)(rbase + l16) * GSTR + quad * 8;
  bf16x8 afr[KTILES];
#pragma unroll
  for (int kt = 0; kt < KTILES; ++kt)
    afr[kt] = *(const bf16x8*)(grow + kt * 32);
  float part[4] = {0.f, 0.f, 0.f, 0.f};
  for (int nt = 0; nt < NTILES_N; ++nt) {
    f32x4 acc = {0.f, 0.f, 0.f, 0.f};
    const bf16x8* bp = (const bf16x8*)Bp + (size_t)nt * KTILES * 64 + lane;
#pragma unroll
    for (int kt = 0; kt < KTILES; ++kt)
      acc = __builtin_amdgcn_mfma_f32_16x16x32_bf16(afr[kt], bp[kt * 64], acc, 0, 0, 0);
    const int n = nt * 16 + l16;
    const float qv = (n < QQ) ? query[n] : 0.f;
    const float bv = (n < QQ) ? lin_b[n] : 0.f;
#pragma unroll
    for (int r = 0; r < 4; ++r)
      part[r] = fmaf(tanhf(acc[r] + bv), qv, part[r]);
  }
#pragma unroll
  for (int r = 0; r < 4; ++r) {
    float p = part[r];
    p += __shfl_xor(p, 1, 64); p += __shfl_xor(p, 2, 64);
    p += __shfl_xor(p, 4, 64); p += __shfl_xor(p, 8, 64);
    if (l16 == 0) logits[rbase + quad * 4 + r] = p;
  }
}

// ---------------------------------------------------------------------------
// News additive attention: softmax over 32 logits + weighted sum of g rows.
// ---------------------------------------------------------------------------
__global__ __launch_bounds__(192) void k_attn_lite(
    const __hip_bfloat16* __restrict__ g, const float* __restrict__ logits,
    float* __restrict__ cand_enc, float* __restrict__ clicked_enc) {
  __shared__ float wgt[32];
  const int b = blockIdx.x, m = blockIdx.y, tid = threadIdx.x;
  if (tid < 32) {
    float lg = logits[(size_t)m * NROW + b * NL + tid];
    float mx = lg;
    for (int o = 16; o; o >>= 1) mx = fmaxf(mx, __shfl_xor(mx, o, 32));
    float e = expf(lg - mx);
    float sm = e;
    for (int o = 16; o; o >>= 1) sm += __shfl_xor(sm, o, 32);
    wgt[tid] = e / sm;
  }
  __syncthreads();
  if (tid < 150) {
    const __hip_bfloat16* base = g + (size_t)(m * NROW + b * NL) * GSTR;
    float a0 = 0.f, a1 = 0.f;
#pragma unroll 8
    for (int l = 0; l < 32; ++l) {
      unsigned u = *(const unsigned*)(base + (size_t)l * GSTR + 2 * tid);
      float w = wgt[l];
      a0 = fmaf(w, __uint_as_float(u << 16), a0);
      a1 = fmaf(w, __uint_as_float(u & 0xffff0000u), a1);
    }
    float* outp = (m < NC) ? (cand_enc + ((size_t)b * NC + m) * DD)
                           : (clicked_enc + ((size_t)b * NH + (m - NC)) * DD);
    outp[2 * tid] = a0; outp[2 * tid + 1] = a1;
  }
}

// User additive attention: softmax over 50 logits + weighted sum.
__global__ __launch_bounds__(192) void k_attn_user_lite(
    const __hip_bfloat16* __restrict__ g, const float* __restrict__ logits,
    float* __restrict__ user_enc) {
  __shared__ float wgt[64];
  const int b = blockIdx.x, tid = threadIdx.x;
  if (tid < 64) {
    float lg = (tid < NH) ? logits[(size_t)b * NH + tid] : -__builtin_inff();
    float mx = lg;
    for (int o = 32; o; o >>= 1) mx = fmaxf(mx, __shfl_xor(mx, o, 64));
    float e = (tid < NH) ? expf(lg - mx) : 0.f;
    float sm = e;
    for (int o = 32; o; o >>= 1) sm += __shfl_xor(sm, o, 64);
    wgt[tid] = e / sm;
  }
  __syncthreads();
  if (tid < 150) {
    const __hip_bfloat16* base = g + (size_t)(b * NH) * GSTR;
    float a0 = 0.f, a1 = 0.f;
#pragma unroll 10
    for (int h = 0; h < NH; ++h) {
      unsigned u = *(const unsigned*)(base + (size_t)h * GSTR + 2 * tid);
      float w = wgt[h];
      a0 = fmaf(w, __uint_as_float(u << 16), a0);
      a1 = fmaf(w, __uint_as_float(u & 0xffff0000u), a1);
    }
    user_enc[(size_t)b * DD + 2 * tid] = a0;
    user_enc[(size_t)b * DD + 2 * tid + 1] = a1;
  }
}

// Final: out[b,c] = cand_enc[b,c,:]·user_enc[b,:]
__global__ __launch_bounds__(64) void k_dot(const float* __restrict__ cand_enc,
                                            const float* __restrict__ user_enc,
                                            float* __restrict__ out) {
  const int bc = blockIdx.x, b = bc / NC, lane = threadIdx.x;
  const float* cp = cand_enc + (size_t)bc * DD;
  const float* up = user_enc + (size_t)b * DD;
  float s = 0.f;
  for (int d = lane; d < DD; d += 64) s = fmaf(cp[d], up[d], s);
  for (int o = 32; o; o >>= 1) s += __shfl_xor(s, o, 64);
  if (lane == 0) out[bc] = s;
}

// ---------------------------------------------------------------------------
extern "C" void kernel_launch(void* const* d_in, const int* in_sizes, int n_in,
                              void* d_out, int out_size, void* d_ws, size_t ws_size,
                              hipStream_t stream) {
  const int* cand = (const int*)d_in[0];
  const int* clicked = (const int*)d_in[1];
  const float* emb = (const float*)d_in[2];
  const float* news_W = (const float*)d_in[3];
  const float* news_a = (const float*)d_in[4];
  const float* news_lw = (const float*)d_in[5];
  const float* news_lb = (const float*)d_in[6];
  const float* news_q = (const float*)d_in[7];
  const float* user_W = (const float*)d_in[8];
  const float* user_a = (const float*)d_in[9];
  const float* user_lw = (const float*)d_in[10];
  const float* user_lb = (const float*)d_in[11];
  const float* user_q = (const float*)d_in[12];
  float* out = (float*)d_out;

  float* W = (float*)d_ws;
  size_t o = 0;
  auto nxt = [&](size_t n) { size_t c = o; o += (n + 63) & ~(size_t)63; return c; };
  float* EW = W + nxt((size_t)NVOC * DD);
  float* s1v = W + nxt(NVOC);
  float* s2v = W + nxt(NVOC);
  float* s2s = W + nxt((size_t)NGAT * NROW);
  int* perm = (int*)(W + nxt((size_t)NGAT * NROW));
  float* E1 = W + nxt((size_t)NGAT * NROW);
  float* E02 = W + nxt((size_t)NGAT * NROW);
  float* C1 = W + nxt((size_t)NGAT * (NT_NEWS + 1) * CW);
  float* C02 = W + nxt((size_t)NGAT * (NT_NEWS + 1) * CW);
  float* cand_enc = W + nxt((size_t)BN_B * NC * DD);
  float* clicked_enc = W + nxt((size_t)BN_B * NH * DD);
  float* WhU = W + nxt((size_t)NUSR * DD);
  float* s1u = W + nxt(NUSR);
  float* s2u = W + nxt(NUSR);
  float* s2sU = W + nxt(NUSR_PAD);
  int* permU = (int*)(W + nxt(NUSR_PAD));
  float* E1U = W + nxt(NUSR_PAD);
  float* E02U = W + nxt(NUSR_PAD);
  float* C1U = W + nxt((size_t)(NT_USER + 1) * CW);
  float* C02U = W + nxt((size_t)(NT_USER + 1) * CW);
  float* user_enc = W + nxt((size_t)BN_B * DD);
  float* logitsN = W + nxt((size_t)NGAT * NROW);
  float* logitsU = W + nxt(NUSR);
  __hip_bfloat16* BpN = (__hip_bfloat16*)(W + nxt((size_t)BPELT * 8 / 2));
  __hip_bfloat16* BpU = (__hip_bfloat16*)(W + nxt((size_t)BPELT * 8 / 2));
  __hip_bfloat16* WhiN = (__hip_bfloat16*)(W + nxt((size_t)WPELT * 8 / 2));
  __hip_bfloat16* WloN = (__hip_bfloat16*)(W + nxt((size_t)WPELT * 8 / 2));
  __hip_bfloat16* WhiU = (__hip_bfloat16*)(W + nxt((size_t)WPELT * 8 / 2));
  __hip_bfloat16* WloU = (__hip_bfloat16*)(W + nxt((size_t)WPELT * 8 / 2));
  __hip_bfloat16* g_news = (__hip_bfloat16*)(W + nxt((size_t)NGAT * NROW * GSTR / 2));
  __hip_bfloat16* g_user = (__hip_bfloat16*)(W + nxt((size_t)NUSR * GSTR / 2));

  const int packgrid = (BPELT + 255) / 256;
  const int packWgrid = (WPELT + 255) / 256;

  // 1. EW = emb @ news_W  (split-bf16 MFMA, ~fp32 accuracy)
  k_packW<<<packWgrid, 256, 0, stream>>>(news_W, WhiN, WloN);
  k_gemm_mfma<<<(NVOC + 63) / 64, 256, 0, stream>>>(emb, WhiN, WloN, EW, NVOC);
  // 2. per-vocab attention scalars
  k_sv<<<(NVOC + 3) / 4, 256, 0, stream>>>(EW, news_a, s1v, s2v, NVOC);
  // 3. sort s2 per news GAT + exp tables
  k_sort<<<NGAT, 1024, 0, stream>>>(cand, clicked, s2v, s2s, perm, E1, E02, 0, NROW, NROW, NROW);
  // 4-5. coarse weighted prefix sums
  k_scan<<<dim3(8, NGAT), 320, 0, stream>>>(EW, perm, E1, E02, C1, C02, NROW, NT_NEWS + 1);
  k_fix<<<NGAT, 320, 0, stream>>>(C1, C02, 8, NT_NEWS + 1);
  // 6. GAT rows -> g_news (bf16, stride 320)
  k_rows<<<dim3(NROW / 8, NGAT), 256, 0, stream>>>(cand, clicked, EW, s1v, s2s, perm, E1, E02,
                                                   C1, C02, g_news, 0, NROW, NT_NEWS, NROW);
  // 7. MFMA logits + lite attention -> cand/clicked encodings
  k_packB<<<packgrid, 256, 0, stream>>>(news_lw, BpN);
  k_logits<<<NGAT * NROW / 64, 256, 0, stream>>>(g_news, BpN, news_lb, news_q, logitsN);
  k_attn_lite<<<dim3(BN_B, NGAT), 192, 0, stream>>>(g_news, logitsN, cand_enc, clicked_enc);
  // 8-12. user GAT over clicked encodings
  k_packW<<<packWgrid, 256, 0, stream>>>(user_W, WhiU, WloU);
  k_gemm_mfma<<<(NUSR + 63) / 64, 256, 0, stream>>>(clicked_enc, WhiU, WloU, WhU, NUSR);
  k_sv<<<NUSR / 4, 256, 0, stream>>>(WhU, user_a, s1u, s2u, NUSR);
  k_sort<<<1, 1024, 0, stream>>>(nullptr, nullptr, s2u, s2sU, permU, E1U, E02U, 1, NUSR, 4096, NUSR_PAD);
  k_scan<<<dim3(13, 1), 320, 0, stream>>>(WhU, permU, E1U, E02U, C1U, C02U, NUSR_PAD, NT_USER + 1);
  k_fix<<<1, 320, 0, stream>>>(C1U, C02U, 13, NT_USER + 1);
  k_rows<<<dim3((NUSR + 7) / 8, 1), 256, 0, stream>>>(nullptr, nullptr, WhU, s1u, s2sU, permU,
                                                      E1U, E02U, C1U, C02U, g_user,
                                                      1, NUSR, NT_USER, NUSR_PAD);
  // 13. user logits + attention
  k_packB<<<packgrid, 256, 0, stream>>>(user_lw, BpU);
  k_logits<<<NUSR / 64, 256, 0, stream>>>(g_user, BpU, user_lb, user_q, logitsU);
  k_attn_user_lite<<<BN_B, 192, 0, stream>>>(g_user, logitsU, user_enc);
  // 14. click score
  k_dot<<<BN_B * NC, 64, 0, stream>>>(cand_enc, user_enc, out);
}